// Round 8
// baseline (601.241 us; speedup 1.0000x reference)
//
#include <hip/hip_runtime.h>
#include <math.h>

#define B_ 128
#define T_ 128
#define NF 76
#define HD 64
#define LQ 77

typedef __attribute__((ext_vector_type(8))) short short8v;
typedef __attribute__((ext_vector_type(4))) short short4v;
typedef __attribute__((ext_vector_type(4))) float f32x4;

__device__ __forceinline__ float frcp(float x) { return __builtin_amdgcn_rcpf(x); }
__device__ __forceinline__ float sigmf(float x) { return frcp(1.0f + __expf(-x)); }
// sigm2: sigmoid with argument already scaled by log2(e) (exp2 domain)
__device__ __forceinline__ float sigm2(float x) { return frcp(1.0f + __builtin_amdgcn_exp2f(-x)); }
__device__ __forceinline__ float tanh_fast(float x) { return 2.0f * frcp(1.0f + __expf(-2.0f * x)) - 1.0f; }
__device__ __forceinline__ short tobf(float x) {
    unsigned u = __float_as_uint(x);
    u += 0x7FFF + ((u >> 16) & 1);   // RNE to bf16
    return (short)(u >> 16);
}
__device__ __forceinline__ float bflo(unsigned u) { return __uint_as_float(u << 16); }
__device__ __forceinline__ float bfhi(unsigned u) { return __uint_as_float(u & 0xffff0000u); }

// ---------------------------------------------------------------------------
// K1a: GRU recurrence via MFMA. R15 structure (measured 139us, best):
// 16 rows, 4 waves, 608 blocks, 8-deep ring, burst stores, bias-in-C,
// exp2-domain gates, setprio around MFMA. R16's fused attention REGRESSED
// (+42us in-kernel vs 29us separate k_att; Hsg readback missed L2) — fusion
// reverted.
// ---------------------------------------------------------------------------
__global__ __launch_bounds__(256) void k_gru0(
    const float* __restrict__ X, const float* __restrict__ Wih,
    const float* __restrict__ Whh, const float* __restrict__ bih,
    const float* __restrict__ bhh,
    const float* __restrict__ Wt, const float* __restrict__ bt,
    const float* __restrict__ Wx, const float* __restrict__ bx,
    short* __restrict__ Hsg, float* __restrict__ qxg, float* __restrict__ qbg)
{
    __shared__ short As[8][16 * 68];    // h ring: As[t&7] = h_t
    __shared__ float xs[16 * 129];
    __shared__ float q1[16 * 65];
    __shared__ float q2[16 * 65];

    const int nf = blockIdx.y;
    const int cbase = blockIdx.x * 16;
    const int tid = threadIdx.x;
    const int w = tid >> 6;
    const int lane = tid & 63;
    const int col = lane & 15;
    const int quad = lane >> 4;

    const float S1 = 1.44269504f;       // log2(e)
    const float S2 = 2.88539008f;       // 2*log2(e)

    for (int i = tid; i < 16 * T_; i += 256) {
        int b = i >> 7, t = i & 127;
        xs[b * 129 + t] = X[((size_t)(cbase + b) * T_ + t) * NF + nf];
    }

    short8v bfr[3][2];
    const float* wbase = Whh + (size_t)nf * 12288;
#pragma unroll
    for (int g3 = 0; g3 < 3; ++g3) {
        const float sc = (g3 == 2) ? S2 : S1;
#pragma unroll
        for (int k2 = 0; k2 < 2; ++k2) {
            int g = 64 * g3 + 16 * w + col;
            const float* src = wbase + g * 64 + 32 * k2 + quad * 8;
            float4 f0 = *(const float4*)src;
            float4 f1 = *(const float4*)(src + 4);
            short8v fr;
            fr[0] = tobf(f0.x * sc); fr[1] = tobf(f0.y * sc);
            fr[2] = tobf(f0.z * sc); fr[3] = tobf(f0.w * sc);
            fr[4] = tobf(f1.x * sc); fr[5] = tobf(f1.y * sc);
            fr[6] = tobf(f1.z * sc); fr[7] = tobf(f1.w * sc);
            bfr[g3][k2] = fr;
        }
    }

    const int c = 16 * w + col;
    const int base = nf * 192;
    const float wr = Wih[base + c] * S1;
    const float wz = Wih[base + 64 + c] * S1;
    const float wn = Wih[base + 128 + c] * S2;
    const float bnn = bih[base + 128 + c] * S2;
    f32x4 biasC[3];
    {
        float brr = (bih[base + c] + bhh[base + c]) * S1;
        float bzz = (bih[base + 64 + c] + bhh[base + 64 + c]) * S1;
        float bhn = bhh[base + 128 + c] * S2;
        biasC[0] = (f32x4){brr, brr, brr, brr};
        biasC[1] = (f32x4){bzz, bzz, bzz, bzz};
        biasC[2] = (f32x4){bhn, bhn, bhn, bhn};
    }

    for (int i = tid; i < 16 * 68; i += 256) As[7][i] = 0;   // h_{-1} = 0
    float hold[4];
#pragma unroll
    for (int r = 0; r < 4; ++r) hold[r] = 0.0f;
    __syncthreads();

    for (int t = 0; t < T_; ++t) {
        const int rb = (t + 7) & 7;     // h_{t-1}
        const int wb = t & 7;           // h_t
        const short* ap = &As[rb][col * 68 + quad * 8];
        short4v a0 = *(const short4v*)ap;
        short4v a1 = *(const short4v*)(ap + 4);
        short4v a2 = *(const short4v*)(ap + 32);
        short4v a3 = *(const short4v*)(ap + 36);
        short8v A0 = {a0[0], a0[1], a0[2], a0[3], a1[0], a1[1], a1[2], a1[3]};
        short8v A1 = {a2[0], a2[1], a2[2], a2[3], a3[0], a3[1], a3[2], a3[3]};

        __builtin_amdgcn_s_setprio(1);
        f32x4 acc[3];
#pragma unroll
        for (int g3 = 0; g3 < 3; ++g3) {
            f32x4 a = __builtin_amdgcn_mfma_f32_16x16x32_bf16(
                A0, bfr[g3][0], biasC[g3], 0, 0, 0);
            acc[g3] = __builtin_amdgcn_mfma_f32_16x16x32_bf16(
                A1, bfr[g3][1], a, 0, 0, 0);
        }
        __builtin_amdgcn_s_setprio(0);

#pragma unroll
        for (int r = 0; r < 4; ++r) {
            float xv = xs[(quad * 4 + r) * 129 + t];
            float rr = sigm2(fmaf(xv, wr, acc[0][r]));
            float zz = sigm2(fmaf(xv, wz, acc[1][r]));
            float uu = sigm2(fmaf(rr, acc[2][r], fmaf(xv, wn, bnn)));
            float nn = fmaf(2.0f, uu, -1.0f);
            hold[r] = fmaf(zz, hold[r] - nn, nn);
        }

#pragma unroll
        for (int r = 0; r < 4; ++r)
            As[wb][(quad * 4 + r) * 68 + c] = tobf(hold[r]);
        __syncthreads();

        if ((t & 7) == 7) {
            // Burst-store h_{t-7}..h_t: LDS reads, barrier, then global stores
            // (drain lands a full step later).
            const int oct = tid & 7, bb = (tid >> 3) & 15, k0 = tid >> 7;
            short4v r0[4], r1[4];
#pragma unroll
            for (int s = 0; s < 4; ++s) {
                const short* p = &As[k0 + 2 * s][bb * 68 + oct * 8];
                r0[s] = *(const short4v*)p;
                r1[s] = *(const short4v*)(p + 4);
            }
            __syncthreads();
            const size_t gbase =
                (((size_t)nf * 128 + cbase + bb) * 128 + (t - 7)) * 64 + oct * 8;
#pragma unroll
            for (int s = 0; s < 4; ++s) {
                short8v v = {r0[s][0], r0[s][1], r0[s][2], r0[s][3],
                             r1[s][0], r1[s][1], r1[s][2], r1[s][3]};
                *(short8v*)(Hsg + gbase + (size_t)(k0 + 2 * s) * 64) = v;
            }
        }
    }

#pragma unroll
    for (int r = 0; r < 4; ++r)
        q1[(quad * 4 + r) * 65 + c] = hold[r];
    __syncthreads();
    for (int o = tid; o < 16 * 64; o += 256) {
        int b = o >> 6, k = o & 63;
        const float* wrow = Wt + ((size_t)nf * 64 + k) * 64;
        float a = bt[nf * 64 + k];
#pragma unroll 8
        for (int h = 0; h < 64; h += 4) {
            float4 wv = *(const float4*)&wrow[h];
            a += q1[b * 65 + h] * wv.x + q1[b * 65 + h + 1] * wv.y
               + q1[b * 65 + h + 2] * wv.z + q1[b * 65 + h + 3] * wv.w;
        }
        q2[b * 65 + k] = a;
    }
    __syncthreads();
    for (int o = tid; o < 16 * 64; o += 256) {
        int b = o >> 6, h = o & 63;
        float a = 0.0f;
#pragma unroll 8
        for (int k = 0; k < 64; ++k)
            a += q2[b * 65 + k] * Wx[((size_t)nf * 64 + k) * 64 + h];
        qxg[((size_t)nf * 128 + cbase + b) * 64 + h] = a;
    }
    for (int b = tid; b < 16; b += 256) {
        float a = 0.0f;
        for (int k = 0; k < 64; ++k) a += q2[b * 65 + k] * bx[nf * 64 + k];
        qbg[nf * 128 + cbase + b] = a;
    }
}

// ---------------------------------------------------------------------------
// K1b: time attention + demo row + S/MU/cnt/cnt2 zeroing. grid (77,128).
// ---------------------------------------------------------------------------
__global__ __launch_bounds__(128) void k_att(
    const short* __restrict__ Hsg, const float* __restrict__ qxg,
    const float* __restrict__ qbg, const float* __restrict__ rate,
    const float* __restrict__ D, const float* __restrict__ dW,
    const float* __restrict__ db, float* __restrict__ Sz,
    float* __restrict__ Fin)
{
    const int nf = blockIdx.x, b = blockIdx.y;
    const int tid = threadIdx.x;

    if (nf == NF) {
        if (tid < 64) {
            float acc = db[tid];
            for (int j = 0; j < 12; ++j) acc += D[b * 12 + j] * dW[tid * 12 + j];
            Fin[((size_t)b * LQ + 76) * HD + tid] = tanh_fast(acc);
        }
        int s0 = b * 33;
        for (int k = tid; k < 33; k += 128) {
            int idx = s0 + k;
            if (idx < 4162) Sz[idx] = 0.0f;   // S[4096] + MU[64] + cnt + cnt2
        }
        return;
    }

    __shared__ float wsum[128 * 69];
    __shared__ float wl[128];
    __shared__ float qxl[64];
    __shared__ float pn[2][68];
    __shared__ float pd[2];
    if (tid < 64) qxl[tid] = qxg[((size_t)nf * 128 + b) * 64 + tid];
    const float qb = qbg[nf * 128 + b];
    const float sigr = sigmf(rate[nf]);

    uint4 rv[8];
    const uint4* src = (const uint4*)(Hsg + (((size_t)nf * 128 + b) * 128 + tid) * 64);
#pragma unroll
    for (int k = 0; k < 8; ++k) rv[k] = src[k];
    __syncthreads();

    float a = qb;
#pragma unroll
    for (int k = 0; k < 8; ++k) {
        a += bflo(rv[k].x) * qxl[k * 8 + 0] + bfhi(rv[k].x) * qxl[k * 8 + 1]
           + bflo(rv[k].y) * qxl[k * 8 + 2] + bfhi(rv[k].y) * qxl[k * 8 + 3]
           + bflo(rv[k].z) * qxl[k * 8 + 4] + bfhi(rv[k].z) * qxl[k * 8 + 5]
           + bflo(rv[k].w) * qxl[k * 8 + 6] + bfhi(rv[k].w) * qxl[k * 8 + 7];
    }
    float ds = sigmf(a);
    float dn = fmaxf(sigr * __logf(2.72f + (1.0f - ds)) * (float)(tid + 1), 1e-6f);
    float e = fmaxf(ds * frcp(dn), 0.0f);
    float w = __expf(e);
    wl[tid] = w;
#pragma unroll
    for (int k = 0; k < 8; ++k) {
        float* d = &wsum[tid * 69 + k * 8];
        d[0] = w * bflo(rv[k].x); d[1] = w * bfhi(rv[k].x);
        d[2] = w * bflo(rv[k].y); d[3] = w * bfhi(rv[k].y);
        d[4] = w * bflo(rv[k].z); d[5] = w * bfhi(rv[k].z);
        d[6] = w * bflo(rv[k].w); d[7] = w * bfhi(rv[k].w);
    }
    __syncthreads();
    {
        int ch = tid & 63, half = tid >> 6;
        float acc = 0.0f, den = 0.0f;
        int t0 = half * 64;
        for (int t = t0; t < t0 + 64; ++t) {
            acc += wsum[t * 69 + ch];
            den += wl[t];
        }
        pn[half][ch] = acc;
        if (ch == 0) pd[half] = den;
    }
    __syncthreads();
    if (tid < 64) {
        float num = pn[0][tid] + pn[1][tid];
        float den = pd[0] + pd[1];
        Fin[((size_t)b * LQ + nf) * HD + tid] = num * frcp(den);
    }
}

// ---------------------------------------------------------------------------
// K4: MHA per (b, head, variant). grid (128,4,2), block 256.
// ---------------------------------------------------------------------------
__global__ __launch_bounds__(256) void k_mha2(
    const float* __restrict__ Fin,
    const float* __restrict__ Wq, const float* __restrict__ bq,
    const float* __restrict__ Wk, const float* __restrict__ bk,
    const float* __restrict__ Wv, const float* __restrict__ bv,
    const float* __restrict__ g1, const float* __restrict__ b1,
    float* __restrict__ M1, float* __restrict__ M2)
{
    __shared__ float xl[LQ * 68];       // later reused as os[231][17]
    __shared__ float qh[LQ * 20], kh[LQ * 20], vh[LQ * 20];
    float (*os)[17] = (float (*)[17])xl;
    const int b = blockIdx.x, hd = blockIdx.y, v = blockIdx.z;
    const int tid = threadIdx.x;
    const float* xsrc = Fin + (size_t)b * LQ * HD;

    for (int idx = tid; idx < LQ * HD; idx += 256)
        xl[(idx >> 6) * 68 + (idx & 63)] = xsrc[idx];
    __syncthreads();
    if (v == 1) {
        if (tid < LQ) {
            float mu = 0.0f;
            for (int h = 0; h < 64; ++h) mu += xl[tid * 68 + h];
            mu *= (1.0f / 64.0f);
            float var = 0.0f;
            for (int h = 0; h < 64; ++h) { float d = xl[tid * 68 + h] - mu; var += d * d; }
            var *= (1.0f / 64.0f);
            float rs = rsqrtf(var + 1e-7f);
            for (int h = 0; h < 64; ++h)
                xl[tid * 68 + h] = (xl[tid * 68 + h] - mu) * rs * g1[h] + b1[h];
        }
        __syncthreads();
    }

    for (int idx = tid; idx < LQ * 16; idx += 256) {
        int l = idx >> 4, d = idx & 15, ch = hd * 16 + d;
        float aq = bq[ch], ak = bk[ch], av = bv[ch];
        const float4* wq = (const float4*)(Wq + ch * 64);
        const float4* wk = (const float4*)(Wk + ch * 64);
        const float4* wv = (const float4*)(Wv + ch * 64);
        const float4* xr = (const float4*)&xl[l * 68];
#pragma unroll 4
        for (int c4 = 0; c4 < 16; ++c4) {
            float4 xv = xr[c4];
            float4 a = wq[c4], bb = wk[c4], cc = wv[c4];
            aq += xv.x * a.x + xv.y * a.y + xv.z * a.z + xv.w * a.w;
            ak += xv.x * bb.x + xv.y * bb.y + xv.z * bb.z + xv.w * bb.w;
            av += xv.x * cc.x + xv.y * cc.y + xv.z * cc.z + xv.w * cc.w;
        }
        qh[l * 20 + d] = aq; kh[l * 20 + d] = ak; vh[l * 20 + d] = av;
    }
    __syncthreads();   // QKV done; xl dead -> reuse as os

    if (tid < 231) {
        int l = tid % 77, third = tid / 77;
        float4 qf0 = *(const float4*)&qh[l * 20 + 0];
        float4 qf1 = *(const float4*)&qh[l * 20 + 4];
        float4 qf2 = *(const float4*)&qh[l * 20 + 8];
        float4 qf3 = *(const float4*)&qh[l * 20 + 12];
        int j0 = third * 26;
        int j1 = (third == 2) ? LQ : j0 + 26;
        float o[16];
#pragma unroll
        for (int d = 0; d < 16; ++d) o[d] = 0.0f;
        float ss = 0.0f;
        for (int j = j0; j < j1; ++j) {
            const float4* kp = (const float4*)&kh[j * 20];
            float4 k0 = kp[0], k1 = kp[1], k2 = kp[2], k3 = kp[3];
            float sc = qf0.x * k0.x + qf0.y * k0.y + qf0.z * k0.z + qf0.w * k0.w
                     + qf1.x * k1.x + qf1.y * k1.y + qf1.z * k1.z + qf1.w * k1.w
                     + qf2.x * k2.x + qf2.y * k2.y + qf2.z * k2.z + qf2.w * k2.w
                     + qf3.x * k3.x + qf3.y * k3.y + qf3.z * k3.z + qf3.w * k3.w;
            float p = __expf(sc * 0.25f);   // scores tiny: no max-shift
            ss += p;
            const float4* vp = (const float4*)&vh[j * 20];
            float4 v0 = vp[0], v1 = vp[1], v2 = vp[2], v3 = vp[3];
            o[0] += p * v0.x; o[1] += p * v0.y; o[2] += p * v0.z; o[3] += p * v0.w;
            o[4] += p * v1.x; o[5] += p * v1.y; o[6] += p * v1.z; o[7] += p * v1.w;
            o[8] += p * v2.x; o[9] += p * v2.y; o[10] += p * v2.z; o[11] += p * v2.w;
            o[12] += p * v3.x; o[13] += p * v3.y; o[14] += p * v3.z; o[15] += p * v3.w;
        }
#pragma unroll
        for (int d = 0; d < 16; ++d) os[tid][d] = o[d];
        os[tid][16] = ss;
    }
    __syncthreads();
    if (tid < LQ) {
        float inv = frcp(os[tid][16] + os[77 + tid][16] + os[154 + tid][16]);
        float* Mout = (v == 1) ? M2 : M1;
#pragma unroll
        for (int d = 0; d < 16; ++d)
            Mout[((size_t)b * LQ + tid) * HD + hd * 16 + d]
                = (os[tid][d] + os[77 + tid][d] + os[154 + tid][d]) * inv;
    }
}

// ---------------------------------------------------------------------------
// K5: fused Y + LN2 + FFN + final-QKV + score, PLUS covariance blocks, PLUS
// merged k_head. grid 616 + 512 + 128 = 1384, block 256.
//  bid <  616 : main zff body; release-increments cnt[1] when done.
//  616..1127  : covariance body (lastf finale writes covout[128]).
//  bid >= 1128: head body — spins (acquire) until cnt[1]==616, then runs
//               softmax + alpha.V + output head for batch b = bid-1128.
// Spinners (128) << co-resident capacity and all other blocks run to
// completion -> no deadlock. Release/acquire at agent scope handles the
// cross-XCD L2 visibility (same pattern as the cov lastf finale).
// ---------------------------------------------------------------------------
__global__ __launch_bounds__(256) void k_zff(
    const float* __restrict__ Fin, float* __restrict__ M2,
    const float* __restrict__ Wo, const float* __restrict__ bo,
    const float* __restrict__ g2, const float* __restrict__ b2,
    const float* __restrict__ W1, const float* __restrict__ bb1,
    const float* __restrict__ W2, const float* __restrict__ bb2,
    const float* __restrict__ faWq, const float* __restrict__ fabq,
    const float* __restrict__ faWk, const float* __restrict__ fabk,
    const float* __restrict__ faWv, const float* __restrict__ fabv,
    const float* __restrict__ faWout, const float* __restrict__ fabout,
    float* __restrict__ scout,
    const float* __restrict__ M1, float* __restrict__ S,
    float* __restrict__ MU, unsigned* __restrict__ cnt,
    float* __restrict__ covout,
    const float* __restrict__ o0W, const float* __restrict__ o0b,
    const float* __restrict__ o1W, const float* __restrict__ o1b)
{
    __shared__ float m2l[16 * 68];
    __shared__ float yl[16 * 68];
    __shared__ float zl[16 * 68];
    __shared__ float ul[16 * 260];
    __shared__ unsigned lastf;
    __shared__ float mus[64];
    __shared__ float pa[4], pd[4];
    const int tid = threadIdx.x;

    if (blockIdx.x >= 1128) {
        // ---- merged k_head: wait for all 616 main blocks (scout + V ready)
        const int b = blockIdx.x - 1128;
        if (tid == 0) {
            while (__hip_atomic_load(&cnt[1], __ATOMIC_ACQUIRE,
                                     __HIP_MEMORY_SCOPE_AGENT) < 616u)
                __builtin_amdgcn_s_sleep(8);
        }
        __syncthreads();
        float* sl = m2l;                         // [80]
        float (*pnh)[64] = (float (*)[64])yl;    // [4][64]
        float* sv = zl;                          // [64]
        float* h1 = zl + 64;                     // [64]
        const float* Vg = M2;
        if (tid < LQ) sl[tid] = scout[b * LQ + tid];
        __syncthreads();
        if (tid < 64) {
            float v0 = sl[tid];
            float v1 = (tid < LQ - 64) ? sl[tid + 64] : -1e30f;
            float m = fmaxf(v0, v1);
            for (int o = 32; o; o >>= 1) m = fmaxf(m, __shfl_xor(m, o, 64));
            float e0 = __expf(v0 - m);
            float e1 = (tid < LQ - 64) ? __expf(v1 - m) : 0.0f;
            float s = e0 + e1;
            for (int o = 32; o; o >>= 1) s += __shfl_xor(s, o, 64);
            sl[tid] = e0;
            if (tid < LQ - 64) sl[tid + 64] = e1;
            if (tid == 0) pa[0] = s;
        }
        __syncthreads();
        {
            const int lo_[5] = {0, 20, 39, 58, 77};
            int h = tid & 63, qd = tid >> 6;
            float acc = 0.0f;
            for (int l = lo_[qd]; l < lo_[qd + 1]; ++l)
                acc += sl[l] * Vg[((size_t)b * LQ + l) * 64 + h];
            pnh[qd][h] = acc;
        }
        __syncthreads();
        if (tid < 64)
            sv[tid] = (pnh[0][tid] + pnh[1][tid] + pnh[2][tid] + pnh[3][tid])
                      * frcp(pa[0]);
        __syncthreads();
        if (tid < 64) {
            float acc = o0b[tid];
            const float4* w4 = (const float4*)(o0W + tid * 64);
#pragma unroll 4
            for (int c4 = 0; c4 < 16; ++c4) {
                float4 wv = w4[c4];
                const float4* sp = (const float4*)&sv[c4 * 4];
                float4 s0 = sp[0];
                acc += s0.x * wv.x + s0.y * wv.y + s0.z * wv.z + s0.w * wv.w;
            }
            h1[tid] = fmaxf(acc, 0.0f);
        }
        __syncthreads();
        if (tid < 64) {
            float p = h1[tid] * o1W[tid];
            for (int o = 32; o; o >>= 1) p += __shfl_xor(p, o, 64);
            if (tid == 0) covout[b] = sigmf(p + o1b[0]);
        }
        return;
    }

    if (blockIdx.x >= 616) {
        // ---- covariance body, tile aliases ul ----
        float* tile = ul;
        const int cid = blockIdx.x - 616;       // 0..511
        const int bxc = cid & 15, byc = cid >> 4;
        const int ig = tid >> 6, j = tid & 63;
        const int i = bxc * 4 + ig;
        const int l0 = byc * 308;               // 32 * 308 = 9856
        float acc = 0.0f, mua = 0.0f;
        for (int c0 = 0; c0 < 308; c0 += 64) {
            int rows = (308 - c0 < 64) ? (308 - c0) : 64;
            __syncthreads();
            const float4* gsrc = (const float4*)(M1 + (size_t)(l0 + c0) * 64);
            for (int idx = tid; idx < rows * 16; idx += 256)
                *(float4*)&tile[idx * 4] = gsrc[idx];
            __syncthreads();
#pragma unroll 4
            for (int l = 0; l < rows; ++l) {
                float v = tile[l * 64 + j];
                acc += tile[l * 64 + i] * v;
                mua += v;
            }
        }
        atomicAdd(&S[i * 64 + j], acc);
        if (bxc == 0 && ig == 0) atomicAdd(&MU[j], mua);
        __threadfence();
        __syncthreads();
        if (tid == 0) lastf = (atomicAdd(cnt, 1u) == 511u);
        __syncthreads();
        if (lastf) {
            if (tid < 64) mus[tid] = atomicAdd(&MU[tid], 0.0f);
            __syncthreads();
            const float invM = 1.0f / 9856.0f;
            float asum = 0.0f, dsum = 0.0f;
            for (int idx = tid; idx < 4096; idx += 256) {
                int ii = idx >> 6, jj = idx & 63;
                float cc = atomicAdd(&S[idx], 0.0f) * invM
                         - (mus[ii] * invM) * (mus[jj] * invM);
                asum += cc * cc;
                if (ii == jj) dsum += cc * cc;
            }
            for (int o = 32; o; o >>= 1) {
                asum += __shfl_xor(asum, o, 64);
                dsum += __shfl_xor(dsum, o, 64);
            }
            if ((tid & 63) == 0) { pa[tid >> 6] = asum; pd[tid >> 6] = dsum; }
            __syncthreads();
            if (tid == 0)
                covout[128] = 0.5f * ((pa[0] + pa[1] + pa[2] + pa[3])
                                    - (pd[0] + pd[1] + pd[2] + pd[3]));
        }
        return;
    }

    const size_t base = (size_t)blockIdx.x * 16;
    const size_t eb = base * 64;
    const int h = tid & 63, rq = tid >> 6;

    for (int idx = tid; idx < 1024; idx += 256)
        m2l[(idx >> 6) * 68 + (idx & 63)] = M2[eb + idx];
    __syncthreads();

    {
        float acc[4];
#pragma unroll
        for (int rr = 0; rr < 4; ++rr) acc[rr] = bo[h];
        const float4* wo = (const float4*)(Wo + h * 64);
#pragma unroll 4
        for (int c4 = 0; c4 < 16; ++c4) {
            float4 wv = wo[c4];
#pragma unroll
            for (int rr = 0; rr < 4; ++rr) {
                float4 mv = *(const float4*)&m2l[(rq * 4 + rr) * 68 + c4 * 4];
                acc[rr] += mv.x * wv.x + mv.y * wv.y + mv.z * wv.z + mv.w * wv.w;
            }
        }
#pragma unroll
        for (int rr = 0; rr < 4; ++rr) {
            int r = rq * 4 + rr;
            yl[r * 68 + h] = Fin[eb + r * 64 + h] + acc[rr];
        }
    }
    __syncthreads();
    {
        // LN2 parallel: 16 rows x 16 lanes; shfl_xor reduce within 16-lane group
        int row = tid >> 4, l16 = tid & 15;
        float s = 0.0f, s2 = 0.0f;
#pragma unroll
        for (int c = l16; c < 64; c += 16) {
            float vv = yl[row * 68 + c];
            s += vv; s2 += vv * vv;
        }
#pragma unroll
        for (int m = 1; m < 16; m <<= 1) {
            s += __shfl_xor(s, m);
            s2 += __shfl_xor(s2, m);
        }
        float mu = s * (1.0f / 64.0f);
        float var = s2 * (1.0f / 64.0f) - mu * mu;
        float rs = rsqrtf(var + 1e-7f);
#pragma unroll
        for (int c = l16; c < 64; c += 16)
            zl[row * 68 + c] = (yl[row * 68 + c] - mu) * rs * g2[c] + b2[c];
    }
    __syncthreads();

    {
        const int f = tid;
        float acc[16];
#pragma unroll
        for (int r = 0; r < 16; ++r) acc[r] = bb1[f];
        const float4* w1r = (const float4*)(W1 + f * 64);
#pragma unroll
        for (int c = 0; c < 4; ++c) {
            float4 w0 = w1r[c * 4 + 0], w1 = w1r[c * 4 + 1];
            float4 w2 = w1r[c * 4 + 2], w3 = w1r[c * 4 + 3];
#pragma unroll
            for (int r = 0; r < 16; ++r) {
                const float4* zr = (const float4*)&zl[r * 68 + c * 16];
                float4 z0 = zr[0], z1 = zr[1], z2 = zr[2], z3 = zr[3];
                acc[r] += z0.x * w0.x + z0.y * w0.y + z0.z * w0.z + z0.w * w0.w
                        + z1.x * w1.x + z1.y * w1.y + z1.z * w1.z + z1.w * w1.w
                        + z2.x * w2.x + z2.y * w2.y + z2.z * w2.z + z2.w * w2.w
                        + z3.x * w3.x + z3.y * w3.y + z3.z * w3.z + z3.w * w3.w;
            }
        }
#pragma unroll
        for (int r = 0; r < 16; ++r) ul[r * 260 + f] = fmaxf(acc[r], 0.0f);
    }
    __syncthreads();
    {
        float acc[4];
#pragma unroll
        for (int rr = 0; rr < 4; ++rr) acc[rr] = bb2[h];
        const float4* w2r = (const float4*)(W2 + h * 256);
#pragma unroll 4
        for (int c = 0; c < 16; ++c) {
            float4 w0 = w2r[c * 4 + 0], w1 = w2r[c * 4 + 1];
            float4 w2 = w2r[c * 4 + 2], w3 = w2r[c * 4 + 3];
#pragma unroll
            for (int rr = 0; rr < 4; ++rr) {
                const float4* ur = (const float4*)&ul[(rq * 4 + rr) * 260 + c * 16];
                float4 u0 = ur[0], u1 = ur[1], u2 = ur[2], u3 = ur[3];
                acc[rr] += u0.x * w0.x + u0.y * w0.y + u0.z * w0.z + u0.w * w0.w
                         + u1.x * w1.x + u1.y * w1.y + u1.z * w1.z + u1.w * w1.w
                         + u2.x * w2.x + u2.y * w2.y + u2.z * w2.z + u2.w * w2.w
                         + u3.x * w3.x + u3.y * w3.y + u3.z * w3.z + u3.w * w3.w;
            }
        }
#pragma unroll
        for (int rr = 0; rr < 4; ++rr)
            yl[(rq * 4 + rr) * 68 + h] += acc[rr];
    }
    __syncthreads();

    {
        const float4* wq = (const float4*)(faWq + h * 64);
        const float4* wk = (const float4*)(faWk + h * 64);
        const float4* wv = (const float4*)(faWv + h * 64);
        float q[4], k[4], v[4];
#pragma unroll
        for (int rr = 0; rr < 4; ++rr) { q[rr] = fabq[h]; k[rr] = fabk[h]; v[rr] = fabv[h]; }
#pragma unroll 4
        for (int c4 = 0; c4 < 16; ++c4) {
            float4 a = wq[c4], bb = wk[c4], cc = wv[c4];
#pragma unroll
            for (int rr = 0; rr < 4; ++rr) {
                float4 zv = *(const float4*)&yl[(rq * 4 + rr) * 68 + c4 * 4];
                q[rr] += zv.x * a.x + zv.y * a.y + zv.z * a.z + zv.w * a.w;
                k[rr] += zv.x * bb.x + zv.y * bb.y + zv.z * bb.z + zv.w * bb.w;
                v[rr] += zv.x * cc.x + zv.y * cc.y + zv.z * cc.z + zv.w * cc.w;
            }
        }
        float fw = faWout[h];
#pragma unroll
        for (int rr = 0; rr < 4; ++rr) {
            int r = rq * 4 + rr;
            ul[r * 68 + h] = q[rr] * k[rr] * fw;
            M2[eb + r * 64 + h] = v[rr];
        }
    }
    __syncthreads();
    if (tid < 16) {
        float a = fabout[0];
        for (int c = 0; c < 64; ++c) a += ul[tid * 68 + c];
        scout[base + tid] = a;
    }
    __syncthreads();
    if (tid == 0)
        __hip_atomic_fetch_add(&cnt[1], 1u, __ATOMIC_RELEASE,
                               __HIP_MEMORY_SCOPE_AGENT);
}

// ---------------------------------------------------------------------------
// Fallback path kernels (ws too small).
// ---------------------------------------------------------------------------
__global__ void k_demo(const float* __restrict__ D, const float* __restrict__ dW,
                       const float* __restrict__ db, float* __restrict__ Fin)
{
    int b = blockIdx.x, h = threadIdx.x;
    float acc = db[h];
    for (int j = 0; j < 12; ++j) acc += D[b * 12 + j] * dW[h * 12 + j];
    Fin[((size_t)b * LQ + 76) * HD + h] = tanh_fast(acc);
}

__global__ void k_zero(float* __restrict__ p)
{
    for (int i = threadIdx.x; i < 4162; i += 256) p[i] = 0.0f;
}

__global__ __launch_bounds__(128) void k_gru_mfma(
    const float* __restrict__ X, const float* __restrict__ Wih,
    const float* __restrict__ Whh, const float* __restrict__ bih,
    const float* __restrict__ bhh,
    const float* __restrict__ Wt, const float* __restrict__ bt,
    const float* __restrict__ Wx, const float* __restrict__ bx,
    const float* __restrict__ rate, float* __restrict__ Fin)
{
    __shared__ short As[2][16 * 68];
    __shared__ float xs[16 * 129];
    __shared__ float q1[16 * 65];
    __shared__ float q2[16 * 65];
    __shared__ float qbs[16];
    __shared__ float dotw[2][2][16];

    const int nf = blockIdx.y;
    const int cbase = blockIdx.x * 16;
    const int tid = threadIdx.x;
    const int w = tid >> 6;
    const int lane = tid & 63;
    const int col = lane & 15;
    const int quad = lane >> 4;

    for (int i = tid; i < 16 * T_; i += 128) {
        int b = i >> 7, t = i & 127;
        xs[b * 129 + t] = X[((size_t)(cbase + b) * T_ + t) * NF + nf];
    }
    short8v bfr[3][2][2];
    const float* wbase = Whh + (size_t)nf * 12288;
#pragma unroll
    for (int g3 = 0; g3 < 3; ++g3)
#pragma unroll
        for (int s = 0; s < 2; ++s)
#pragma unroll
            for (int k2 = 0; k2 < 2; ++k2) {
                int g = 64 * g3 + 32 * w + 16 * s + col;
                const float* src = wbase + g * 64 + 32 * k2 + quad * 8;
                float4 f0 = *(const float4*)src;
                float4 f1 = *(const float4*)(src + 4);
                short8v fr;
                fr[0] = tobf(f0.x); fr[1] = tobf(f0.y); fr[2] = tobf(f0.z); fr[3] = tobf(f0.w);
                fr[4] = tobf(f1.x); fr[5] = tobf(f1.y); fr[6] = tobf(f1.z); fr[7] = tobf(f1.w);
                bfr[g3][s][k2] = fr;
            }
    float wr[2], wz[2], wn[2], br[2], bz[2], bnn[2], bhn[2];
#pragma unroll
    for (int s = 0; s < 2; ++s) {
        int c = 32 * w + 16 * s + col;
        int base = nf * 192;
        wr[s] = Wih[base + c]; wz[s] = Wih[base + 64 + c]; wn[s] = Wih[base + 128 + c];
        br[s] = bih[base + c] + bhh[base + c];
        bz[s] = bih[base + 64 + c] + bhh[base + 64 + c];
        bnn[s] = bih[base + 128 + c]; bhn[s] = bhh[base + 128 + c];
    }
    const float sigr = sigmf(rate[nf]);
    float hold[2][4], num[2][4], den[4], qxv[2][4], qbv[4];
#pragma unroll
    for (int r = 0; r < 4; ++r) {
        den[r] = 0.0f; qbv[r] = 0.0f;
        num[0][r] = 0.0f; num[1][r] = 0.0f;
        qxv[0][r] = 0.0f; qxv[1][r] = 0.0f;
    }
    for (int pass = 0; pass < 2; ++pass) {
        for (int i = tid; i < 16 * 68; i += 128) As[0][i] = 0;
#pragma unroll
        for (int s = 0; s < 2; ++s)
#pragma unroll
            for (int r = 0; r < 4; ++r) hold[s][r] = 0.0f;
        __syncthreads();
        for (int t = 0; t < T_; ++t) {
            const int rb = t & 1;
            const int wb = 1 - rb;
            const short* ap = &As[rb][col * 68 + quad * 8];
            short4v a0 = *(const short4v*)ap;
            short4v a1 = *(const short4v*)(ap + 4);
            short4v a2 = *(const short4v*)(ap + 32);
            short4v a3 = *(const short4v*)(ap + 36);
            short8v A0 = {a0[0], a0[1], a0[2], a0[3], a1[0], a1[1], a1[2], a1[3]};
            short8v A1 = {a2[0], a2[1], a2[2], a2[3], a3[0], a3[1], a3[2], a3[3]};
            f32x4 acc[3][2];
#pragma unroll
            for (int g3 = 0; g3 < 3; ++g3)
#pragma unroll
                for (int s = 0; s < 2; ++s) {
                    f32x4 a = {0.0f, 0.0f, 0.0f, 0.0f};
                    a = __builtin_amdgcn_mfma_f32_16x16x32_bf16(A0, bfr[g3][s][0], a, 0, 0, 0);
                    a = __builtin_amdgcn_mfma_f32_16x16x32_bf16(A1, bfr[g3][s][1], a, 0, 0, 0);
                    acc[g3][s] = a;
                }
            float xv[4];
#pragma unroll
            for (int r = 0; r < 4; ++r) xv[r] = xs[(quad * 4 + r) * 129 + t];
            float hnew[2][4];
#pragma unroll
            for (int s = 0; s < 2; ++s)
#pragma unroll
                for (int r = 0; r < 4; ++r) {
                    float rr = sigmf(xv[r] * wr[s] + br[s] + acc[0][s][r]);
                    float zz = sigmf(xv[r] * wz[s] + bz[s] + acc[1][s][r]);
                    float nn = tanh_fast(xv[r] * wn[s] + bnn[s] + rr * (acc[2][s][r] + bhn[s]));
                    hnew[s][r] = (1.0f - zz) * nn + zz * hold[s][r];
                    hold[s][r] = hnew[s][r];
                }
#pragma unroll
            for (int s = 0; s < 2; ++s)
#pragma unroll
                for (int r = 0; r < 4; ++r)
                    As[wb][(quad * 4 + r) * 68 + 32 * w + 16 * s + col] = tobf(hnew[s][r]);
            if (pass == 1) {
                float p[4];
#pragma unroll
                for (int r = 0; r < 4; ++r)
                    p[r] = qxv[0][r] * hnew[0][r] + qxv[1][r] * hnew[1][r];
#pragma unroll
                for (int m = 1; m < 16; m <<= 1) {
                    p[0] += __shfl_xor(p[0], m, 64);
                    p[1] += __shfl_xor(p[1], m, 64);
                    p[2] += __shfl_xor(p[2], m, 64);
                    p[3] += __shfl_xor(p[3], m, 64);
                }
                if (col == 0) {
#pragma unroll
                    for (int r = 0; r < 4; ++r) dotw[rb][w][quad * 4 + r] = p[r];
                }
                __syncthreads();
                float tf = (float)(t + 1);
#pragma unroll
                for (int r = 0; r < 4; ++r) {
                    float dot = p[r] + dotw[rb][1 - w][quad * 4 + r] + qbv[r];
                    float ds = sigmf(dot);
                    float dn = fmaxf(sigr * __logf(2.72f + (1.0f - ds)) * tf, 1e-6f);
                    float e = fmaxf(ds * frcp(dn), 0.0f);
                    float wt = __expf(e);
                    den[r] += wt;
                    num[0][r] += wt * hnew[0][r];
                    num[1][r] += wt * hnew[1][r];
                }
            } else {
                __syncthreads();
            }
        }
        if (pass == 0) {
#pragma unroll
            for (int s = 0; s < 2; ++s)
#pragma unroll
                for (int r = 0; r < 4; ++r)
                    q1[(quad * 4 + r) * 65 + 32 * w + 16 * s + col] = hold[s][r];
            __syncthreads();
            for (int o = tid; o < 16 * 64; o += 128) {
                int b = o >> 6, k = o & 63;
                const float* wrow = Wt + ((size_t)nf * 64 + k) * 64;
                float a = bt[nf * 64 + k];
#pragma unroll 8
                for (int h = 0; h < 64; h += 4) {
                    float4 wv = *(const float4*)&wrow[h];
                    a += q1[b * 65 + h] * wv.x + q1[b * 65 + h + 1] * wv.y
                       + q1[b * 65 + h + 2] * wv.z + q1[b * 65 + h + 3] * wv.w;
                }
                q2[b * 65 + k] = a;
            }
            __syncthreads();
            for (int o = tid; o < 16 * 64; o += 128) {
                int b = o >> 6, h = o & 63;
                float a = 0.0f;
#pragma unroll 8
                for (int k = 0; k < 64; ++k)
                    a += q2[b * 65 + k] * Wx[((size_t)nf * 64 + k) * 64 + h];
                q1[b * 65 + h] = a;
            }
            for (int b = tid; b < 16; b += 128) {
                float a = 0.0f;
                for (int k = 0; k < 64; ++k) a += q2[b * 65 + k] * bx[nf * 64 + k];
                qbs[b] = a;
            }
            __syncthreads();
#pragma unroll
            for (int r = 0; r < 4; ++r) {
                qbv[r] = qbs[quad * 4 + r];
#pragma unroll
                for (int s = 0; s < 2; ++s)
                    qxv[s][r] = q1[(quad * 4 + r) * 65 + 32 * w + 16 * s + col];
                den[r] = 0.0f; num[0][r] = 0.0f; num[1][r] = 0.0f;
            }
            __syncthreads();
        }
    }
#pragma unroll
    for (int s = 0; s < 2; ++s)
#pragma unroll
        for (int r = 0; r < 4; ++r) {
            int b = cbase + quad * 4 + r;
            int c = 32 * w + 16 * s + col;
            Fin[((size_t)b * LQ + nf) * HD + c] = num[s][r] * frcp(den[r]);
        }
}

extern "C" void kernel_launch(void* const* d_in, const int* in_sizes, int n_in,
                              void* d_out, int out_size, void* d_ws, size_t ws_size,
                              hipStream_t stream)
{
    (void)in_sizes; (void)n_in; (void)out_size;
    const float* X     = (const float*)d_in[0];
    const float* D     = (const float*)d_in[1];
    const float* gWih  = (const float*)d_in[2];
    const float* gWhh  = (const float*)d_in[3];
    const float* gbih  = (const float*)d_in[4];
    const float* gbhh  = (const float*)d_in[5];
    const float* aWt   = (const float*)d_in[6];
    const float* abt   = (const float*)d_in[7];
    const float* aWx   = (const float*)d_in[8];
    const float* abx   = (const float*)d_in[9];
    const float* arate = (const float*)d_in[10];
    const float* dW    = (const float*)d_in[11];
    const float* db    = (const float*)d_in[12];
    const float* mWq   = (const float*)d_in[13]; const float* mbq = (const float*)d_in[14];
    const float* mWk   = (const float*)d_in[15]; const float* mbk = (const float*)d_in[16];
    const float* mWv   = (const float*)d_in[17]; const float* mbv = (const float*)d_in[18];
    const float* mWo   = (const float*)d_in[19]; const float* mbo = (const float*)d_in[20];
    const float* l1g   = (const float*)d_in[21]; const float* l1b = (const float*)d_in[22];
    const float* fW1   = (const float*)d_in[23]; const float* fb1 = (const float*)d_in[24];
    const float* fW2   = (const float*)d_in[25]; const float* fb2 = (const float*)d_in[26];
    const float* l2g   = (const float*)d_in[27]; const float* l2b = (const float*)d_in[28];
    const float* faWq  = (const float*)d_in[29]; const float* fabq = (const float*)d_in[30];
    const float* faWk  = (const float*)d_in[31]; const float* fabk = (const float*)d_in[32];
    const float* faWv  = (const float*)d_in[33]; const float* fabv = (const float*)d_in[34];
    const float* faWo  = (const float*)d_in[35]; const float* fabo = (const float*)d_in[36];
    const float* o0W   = (const float*)d_in[37]; const float* o0b  = (const float*)d_in[38];
    const float* o1W   = (const float*)d_in[39]; const float* o1b  = (const float*)d_in[40];

    float* ws  = (float*)d_ws;
    float* Fin = ws;                               // 630,784
    float* M1  = Fin + 630784;                     // 630,784
    float* M2  = M1  + 630784;                     // 630,784 (later reused as V)
    float* S   = M2  + 630784;                     // 4096
    float* MU  = S   + 4096;                       // 64
    unsigned* cnt = (unsigned*)(MU + 64);          // cnt[0]=cov, cnt[1]=zff-main gate
    float* qxg = MU + 128;                         // 622,592
    float* scout = qxg + 622592;                   // 9,856 (also used as qbg)
    short* Hsg = (short*)(scout + 9856);           // 79,691,776 shorts (bf16)
    const size_t need = (size_t)(630784 * 3 + 4096 + 128 + 622592 + 9856) * 4
                        + (size_t)79691776 * 2;
    float* outp = (float*)d_out;
    float* qbg = scout;                            // alias: qbg consumed before scout written

    if (ws_size >= need) {
        k_gru0<<<dim3(8, NF), 256, 0, stream>>>(X, gWih, gWhh, gbih, gbhh,
                                                aWt, abt, aWx, abx, Hsg, qxg, qbg);
        k_att<<<dim3(NF + 1, B_), 128, 0, stream>>>(Hsg, qxg, qbg, arate,
                                                    D, dW, db, S, Fin);
    } else {
        k_gru_mfma<<<dim3(8, NF), 128, 0, stream>>>(X, gWih, gWhh, gbih, gbhh,
                                                    aWt, abt, aWx, abx, arate, Fin);
        k_demo<<<B_, 64, 0, stream>>>(D, dW, db, Fin);
        k_zero<<<1, 256, 0, stream>>>(S);
    }
    k_mha2<<<dim3(B_, 4, 2), 256, 0, stream>>>(Fin, mWq, mbq, mWk, mbk, mWv, mbv,
                                               l1g, l1b, M1, M2);
    k_zff<<<1384, 256, 0, stream>>>(Fin, M2, mWo, mbo, l2g, l2b,
                                    fW1, fb1, fW2, fb2,
                                    faWq, fabq, faWk, fabk, faWv, fabv,
                                    faWo, fabo, scout,
                                    M1, S, MU, cnt, outp,
                                    o0W, o0b, o1W, o1b);
}

// Round 9
// 500.191 us; speedup vs baseline: 1.2020x; 1.2020x over previous
//
#include <hip/hip_runtime.h>
#include <math.h>

#define B_ 128
#define T_ 128
#define NF 76
#define HD 64
#define LQ 77

typedef __attribute__((ext_vector_type(8))) short short8v;
typedef __attribute__((ext_vector_type(4))) short short4v;
typedef __attribute__((ext_vector_type(4))) float f32x4;

__device__ __forceinline__ float frcp(float x) { return __builtin_amdgcn_rcpf(x); }
__device__ __forceinline__ float sigmf(float x) { return frcp(1.0f + __expf(-x)); }
// sigm2: sigmoid with argument already scaled by log2(e) (exp2 domain)
__device__ __forceinline__ float sigm2(float x) { return frcp(1.0f + __builtin_amdgcn_exp2f(-x)); }
__device__ __forceinline__ float tanh_fast(float x) { return 2.0f * frcp(1.0f + __expf(-2.0f * x)) - 1.0f; }
__device__ __forceinline__ short tobf(float x) {
    unsigned u = __float_as_uint(x);
    u += 0x7FFF + ((u >> 16) & 1);   // RNE to bf16
    return (short)(u >> 16);
}
__device__ __forceinline__ float bflo(unsigned u) { return __uint_as_float(u << 16); }
__device__ __forceinline__ float bfhi(unsigned u) { return __uint_as_float(u & 0xffff0000u); }

// ---------------------------------------------------------------------------
// K1a: GRU recurrence via MFMA. R15 structure (measured 139us, best):
// 16 rows, 4 waves, 608 blocks, 8-deep ring, burst stores, bias-in-C,
// exp2-domain gates, setprio around MFMA.
// R18: grid flattened to 608 1-D; chunk = bid/76, nf = bid%76 puts the 8
// chunks of one nf on 2 XCDs (round-robin +76 == +4 mod 8) instead of 8,
// cutting Whh refetch. Spin-merges (R17) and in-kernel attention (R16)
// both regressed and are permanently rejected.
// ---------------------------------------------------------------------------
__global__ __launch_bounds__(256) void k_gru0(
    const float* __restrict__ X, const float* __restrict__ Wih,
    const float* __restrict__ Whh, const float* __restrict__ bih,
    const float* __restrict__ bhh,
    const float* __restrict__ Wt, const float* __restrict__ bt,
    const float* __restrict__ Wx, const float* __restrict__ bx,
    short* __restrict__ Hsg, float* __restrict__ qxg, float* __restrict__ qbg)
{
    __shared__ short As[8][16 * 68];    // h ring: As[t&7] = h_t
    __shared__ float xs[16 * 129];
    __shared__ float q1[16 * 65];
    __shared__ float q2[16 * 65];

    const int nf = blockIdx.x % NF;
    const int cbase = (blockIdx.x / NF) * 16;
    const int tid = threadIdx.x;
    const int w = tid >> 6;
    const int lane = tid & 63;
    const int col = lane & 15;
    const int quad = lane >> 4;

    const float S1 = 1.44269504f;       // log2(e)
    const float S2 = 2.88539008f;       // 2*log2(e)

    for (int i = tid; i < 16 * T_; i += 256) {
        int b = i >> 7, t = i & 127;
        xs[b * 129 + t] = X[((size_t)(cbase + b) * T_ + t) * NF + nf];
    }

    short8v bfr[3][2];
    const float* wbase = Whh + (size_t)nf * 12288;
#pragma unroll
    for (int g3 = 0; g3 < 3; ++g3) {
        const float sc = (g3 == 2) ? S2 : S1;
#pragma unroll
        for (int k2 = 0; k2 < 2; ++k2) {
            int g = 64 * g3 + 16 * w + col;
            const float* src = wbase + g * 64 + 32 * k2 + quad * 8;
            float4 f0 = *(const float4*)src;
            float4 f1 = *(const float4*)(src + 4);
            short8v fr;
            fr[0] = tobf(f0.x * sc); fr[1] = tobf(f0.y * sc);
            fr[2] = tobf(f0.z * sc); fr[3] = tobf(f0.w * sc);
            fr[4] = tobf(f1.x * sc); fr[5] = tobf(f1.y * sc);
            fr[6] = tobf(f1.z * sc); fr[7] = tobf(f1.w * sc);
            bfr[g3][k2] = fr;
        }
    }

    const int c = 16 * w + col;
    const int base = nf * 192;
    const float wr = Wih[base + c] * S1;
    const float wz = Wih[base + 64 + c] * S1;
    const float wn = Wih[base + 128 + c] * S2;
    const float bnn = bih[base + 128 + c] * S2;
    f32x4 biasC[3];
    {
        float brr = (bih[base + c] + bhh[base + c]) * S1;
        float bzz = (bih[base + 64 + c] + bhh[base + 64 + c]) * S1;
        float bhn = bhh[base + 128 + c] * S2;
        biasC[0] = (f32x4){brr, brr, brr, brr};
        biasC[1] = (f32x4){bzz, bzz, bzz, bzz};
        biasC[2] = (f32x4){bhn, bhn, bhn, bhn};
    }

    for (int i = tid; i < 16 * 68; i += 256) As[7][i] = 0;   // h_{-1} = 0
    float hold[4];
#pragma unroll
    for (int r = 0; r < 4; ++r) hold[r] = 0.0f;
    __syncthreads();

    for (int t = 0; t < T_; ++t) {
        const int rb = (t + 7) & 7;     // h_{t-1}
        const int wb = t & 7;           // h_t
        const short* ap = &As[rb][col * 68 + quad * 8];
        short4v a0 = *(const short4v*)ap;
        short4v a1 = *(const short4v*)(ap + 4);
        short4v a2 = *(const short4v*)(ap + 32);
        short4v a3 = *(const short4v*)(ap + 36);
        short8v A0 = {a0[0], a0[1], a0[2], a0[3], a1[0], a1[1], a1[2], a1[3]};
        short8v A1 = {a2[0], a2[1], a2[2], a2[3], a3[0], a3[1], a3[2], a3[3]};

        __builtin_amdgcn_s_setprio(1);
        f32x4 acc[3];
#pragma unroll
        for (int g3 = 0; g3 < 3; ++g3) {
            f32x4 a = __builtin_amdgcn_mfma_f32_16x16x32_bf16(
                A0, bfr[g3][0], biasC[g3], 0, 0, 0);
            acc[g3] = __builtin_amdgcn_mfma_f32_16x16x32_bf16(
                A1, bfr[g3][1], a, 0, 0, 0);
        }
        __builtin_amdgcn_s_setprio(0);

#pragma unroll
        for (int r = 0; r < 4; ++r) {
            float xv = xs[(quad * 4 + r) * 129 + t];
            float rr = sigm2(fmaf(xv, wr, acc[0][r]));
            float zz = sigm2(fmaf(xv, wz, acc[1][r]));
            float uu = sigm2(fmaf(rr, acc[2][r], fmaf(xv, wn, bnn)));
            float nn = fmaf(2.0f, uu, -1.0f);
            hold[r] = fmaf(zz, hold[r] - nn, nn);
        }

#pragma unroll
        for (int r = 0; r < 4; ++r)
            As[wb][(quad * 4 + r) * 68 + c] = tobf(hold[r]);
        __syncthreads();

        if ((t & 7) == 7) {
            // Burst-store h_{t-7}..h_t: LDS reads, barrier, then global stores
            // (drain lands a full step later).
            const int oct = tid & 7, bb = (tid >> 3) & 15, k0 = tid >> 7;
            short4v r0[4], r1[4];
#pragma unroll
            for (int s = 0; s < 4; ++s) {
                const short* p = &As[k0 + 2 * s][bb * 68 + oct * 8];
                r0[s] = *(const short4v*)p;
                r1[s] = *(const short4v*)(p + 4);
            }
            __syncthreads();
            const size_t gbase =
                (((size_t)nf * 128 + cbase + bb) * 128 + (t - 7)) * 64 + oct * 8;
#pragma unroll
            for (int s = 0; s < 4; ++s) {
                short8v v = {r0[s][0], r0[s][1], r0[s][2], r0[s][3],
                             r1[s][0], r1[s][1], r1[s][2], r1[s][3]};
                *(short8v*)(Hsg + gbase + (size_t)(k0 + 2 * s) * 64) = v;
            }
        }
    }

#pragma unroll
    for (int r = 0; r < 4; ++r)
        q1[(quad * 4 + r) * 65 + c] = hold[r];
    __syncthreads();
    for (int o = tid; o < 16 * 64; o += 256) {
        int b = o >> 6, k = o & 63;
        const float* wrow = Wt + ((size_t)nf * 64 + k) * 64;
        float a = bt[nf * 64 + k];
#pragma unroll 8
        for (int h = 0; h < 64; h += 4) {
            float4 wv = *(const float4*)&wrow[h];
            a += q1[b * 65 + h] * wv.x + q1[b * 65 + h + 1] * wv.y
               + q1[b * 65 + h + 2] * wv.z + q1[b * 65 + h + 3] * wv.w;
        }
        q2[b * 65 + k] = a;
    }
    __syncthreads();
    for (int o = tid; o < 16 * 64; o += 256) {
        int b = o >> 6, h = o & 63;
        float a = 0.0f;
#pragma unroll 8
        for (int k = 0; k < 64; ++k)
            a += q2[b * 65 + k] * Wx[((size_t)nf * 64 + k) * 64 + h];
        qxg[((size_t)nf * 128 + cbase + b) * 64 + h] = a;
    }
    for (int b = tid; b < 16; b += 256) {
        float a = 0.0f;
        for (int k = 0; k < 64; ++k) a += q2[b * 65 + k] * bx[nf * 64 + k];
        qbg[nf * 128 + cbase + b] = a;
    }
}

// ---------------------------------------------------------------------------
// K1b: time attention + demo row + S/MU/counter zeroing. grid (77,128).
// ---------------------------------------------------------------------------
__global__ __launch_bounds__(128) void k_att(
    const short* __restrict__ Hsg, const float* __restrict__ qxg,
    const float* __restrict__ qbg, const float* __restrict__ rate,
    const float* __restrict__ D, const float* __restrict__ dW,
    const float* __restrict__ db, float* __restrict__ Sz,
    float* __restrict__ Fin)
{
    const int nf = blockIdx.x, b = blockIdx.y;
    const int tid = threadIdx.x;

    if (nf == NF) {
        if (tid < 64) {
            float acc = db[tid];
            for (int j = 0; j < 12; ++j) acc += D[b * 12 + j] * dW[tid * 12 + j];
            Fin[((size_t)b * LQ + 76) * HD + tid] = tanh_fast(acc);
        }
        int s0 = b * 33;
        for (int k = tid; k < 33; k += 128) {
            int idx = s0 + k;
            if (idx < 4161) Sz[idx] = 0.0f;
        }
        return;
    }

    __shared__ float wsum[128 * 69];
    __shared__ float wl[128];
    __shared__ float qxl[64];
    __shared__ float pn[2][68];
    __shared__ float pd[2];
    if (tid < 64) qxl[tid] = qxg[((size_t)nf * 128 + b) * 64 + tid];
    const float qb = qbg[nf * 128 + b];
    const float sigr = sigmf(rate[nf]);

    uint4 rv[8];
    const uint4* src = (const uint4*)(Hsg + (((size_t)nf * 128 + b) * 128 + tid) * 64);
#pragma unroll
    for (int k = 0; k < 8; ++k) rv[k] = src[k];
    __syncthreads();

    float a = qb;
#pragma unroll
    for (int k = 0; k < 8; ++k) {
        a += bflo(rv[k].x) * qxl[k * 8 + 0] + bfhi(rv[k].x) * qxl[k * 8 + 1]
           + bflo(rv[k].y) * qxl[k * 8 + 2] + bfhi(rv[k].y) * qxl[k * 8 + 3]
           + bflo(rv[k].z) * qxl[k * 8 + 4] + bfhi(rv[k].z) * qxl[k * 8 + 5]
           + bflo(rv[k].w) * qxl[k * 8 + 6] + bfhi(rv[k].w) * qxl[k * 8 + 7];
    }
    float ds = sigmf(a);
    float dn = fmaxf(sigr * __logf(2.72f + (1.0f - ds)) * (float)(tid + 1), 1e-6f);
    float e = fmaxf(ds * frcp(dn), 0.0f);
    float w = __expf(e);
    wl[tid] = w;
#pragma unroll
    for (int k = 0; k < 8; ++k) {
        float* d = &wsum[tid * 69 + k * 8];
        d[0] = w * bflo(rv[k].x); d[1] = w * bfhi(rv[k].x);
        d[2] = w * bflo(rv[k].y); d[3] = w * bfhi(rv[k].y);
        d[4] = w * bflo(rv[k].z); d[5] = w * bfhi(rv[k].z);
        d[6] = w * bflo(rv[k].w); d[7] = w * bfhi(rv[k].w);
    }
    __syncthreads();
    {
        int ch = tid & 63, half = tid >> 6;
        float acc = 0.0f, den = 0.0f;
        int t0 = half * 64;
        for (int t = t0; t < t0 + 64; ++t) {
            acc += wsum[t * 69 + ch];
            den += wl[t];
        }
        pn[half][ch] = acc;
        if (ch == 0) pd[half] = den;
    }
    __syncthreads();
    if (tid < 64) {
        float num = pn[0][tid] + pn[1][tid];
        float den = pd[0] + pd[1];
        Fin[((size_t)b * LQ + nf) * HD + tid] = num * frcp(den);
    }
}

// ---------------------------------------------------------------------------
// K4: MHA per (b, head, variant). grid (128,4,2), block 256.
// R18: LN (v==1) parallelized to 4 lanes/row + shfl_xor reduce (replaces the
// 77-thread serial 192-op loops).
// ---------------------------------------------------------------------------
__global__ __launch_bounds__(256) void k_mha2(
    const float* __restrict__ Fin,
    const float* __restrict__ Wq, const float* __restrict__ bq,
    const float* __restrict__ Wk, const float* __restrict__ bk,
    const float* __restrict__ Wv, const float* __restrict__ bv,
    const float* __restrict__ g1, const float* __restrict__ b1,
    float* __restrict__ M1, float* __restrict__ M2)
{
    __shared__ float xl[LQ * 68];       // later reused as os[231][17]
    __shared__ float qh[LQ * 20], kh[LQ * 20], vh[LQ * 20];
    float (*os)[17] = (float (*)[17])xl;
    const int b = blockIdx.x, hd = blockIdx.y, v = blockIdx.z;
    const int tid = threadIdx.x;
    const float* xsrc = Fin + (size_t)b * LQ * HD;

    for (int idx = tid; idx < LQ * HD; idx += 256)
        xl[(idx >> 6) * 68 + (idx & 63)] = xsrc[idx];
    __syncthreads();
    if (v == 1) {
        int r4 = tid >> 2, l4 = tid & 3;
        for (int row = r4; row < LQ; row += 64) {
            float s = 0.0f, s2 = 0.0f;
            for (int cc = l4; cc < 64; cc += 4) {
                float vv = xl[row * 68 + cc];
                s += vv; s2 += vv * vv;
            }
            s += __shfl_xor(s, 1);  s += __shfl_xor(s, 2);
            s2 += __shfl_xor(s2, 1); s2 += __shfl_xor(s2, 2);
            float mu = s * (1.0f / 64.0f);
            float var = s2 * (1.0f / 64.0f) - mu * mu;
            float rs = rsqrtf(var + 1e-7f);
            for (int cc = l4; cc < 64; cc += 4)
                xl[row * 68 + cc] = (xl[row * 68 + cc] - mu) * rs * g1[cc] + b1[cc];
        }
        __syncthreads();
    }

    for (int idx = tid; idx < LQ * 16; idx += 256) {
        int l = idx >> 4, d = idx & 15, ch = hd * 16 + d;
        float aq = bq[ch], ak = bk[ch], av = bv[ch];
        const float4* wq = (const float4*)(Wq + ch * 64);
        const float4* wk = (const float4*)(Wk + ch * 64);
        const float4* wv = (const float4*)(Wv + ch * 64);
        const float4* xr = (const float4*)&xl[l * 68];
#pragma unroll 4
        for (int c4 = 0; c4 < 16; ++c4) {
            float4 xv = xr[c4];
            float4 a = wq[c4], bb = wk[c4], cc = wv[c4];
            aq += xv.x * a.x + xv.y * a.y + xv.z * a.z + xv.w * a.w;
            ak += xv.x * bb.x + xv.y * bb.y + xv.z * bb.z + xv.w * bb.w;
            av += xv.x * cc.x + xv.y * cc.y + xv.z * cc.z + xv.w * cc.w;
        }
        qh[l * 20 + d] = aq; kh[l * 20 + d] = ak; vh[l * 20 + d] = av;
    }
    __syncthreads();   // QKV done; xl dead -> reuse as os

    if (tid < 231) {
        int l = tid % 77, third = tid / 77;
        float4 qf0 = *(const float4*)&qh[l * 20 + 0];
        float4 qf1 = *(const float4*)&qh[l * 20 + 4];
        float4 qf2 = *(const float4*)&qh[l * 20 + 8];
        float4 qf3 = *(const float4*)&qh[l * 20 + 12];
        int j0 = third * 26;
        int j1 = (third == 2) ? LQ : j0 + 26;
        float o[16];
#pragma unroll
        for (int d = 0; d < 16; ++d) o[d] = 0.0f;
        float ss = 0.0f;
        for (int j = j0; j < j1; ++j) {
            const float4* kp = (const float4*)&kh[j * 20];
            float4 k0 = kp[0], k1 = kp[1], k2 = kp[2], k3 = kp[3];
            float sc = qf0.x * k0.x + qf0.y * k0.y + qf0.z * k0.z + qf0.w * k0.w
                     + qf1.x * k1.x + qf1.y * k1.y + qf1.z * k1.z + qf1.w * k1.w
                     + qf2.x * k2.x + qf2.y * k2.y + qf2.z * k2.z + qf2.w * k2.w
                     + qf3.x * k3.x + qf3.y * k3.y + qf3.z * k3.z + qf3.w * k3.w;
            float p = __expf(sc * 0.25f);   // scores tiny: no max-shift
            ss += p;
            const float4* vp = (const float4*)&vh[j * 20];
            float4 v0 = vp[0], v1 = vp[1], v2 = vp[2], v3 = vp[3];
            o[0] += p * v0.x; o[1] += p * v0.y; o[2] += p * v0.z; o[3] += p * v0.w;
            o[4] += p * v1.x; o[5] += p * v1.y; o[6] += p * v1.z; o[7] += p * v1.w;
            o[8] += p * v2.x; o[9] += p * v2.y; o[10] += p * v2.z; o[11] += p * v2.w;
            o[12] += p * v3.x; o[13] += p * v3.y; o[14] += p * v3.z; o[15] += p * v3.w;
        }
#pragma unroll
        for (int d = 0; d < 16; ++d) os[tid][d] = o[d];
        os[tid][16] = ss;
    }
    __syncthreads();
    if (tid < LQ) {
        float inv = frcp(os[tid][16] + os[77 + tid][16] + os[154 + tid][16]);
        float* Mout = (v == 1) ? M2 : M1;
#pragma unroll
        for (int d = 0; d < 16; ++d)
            Mout[((size_t)b * LQ + tid) * HD + hd * 16 + d]
                = (os[tid][d] + os[77 + tid][d] + os[154 + tid][d]) * inv;
    }
}

// ---------------------------------------------------------------------------
// K5: fused Y + LN2 + FFN + final-QKV + score, PLUS covariance blocks.
// grid 616 + 512 = 1128, block 256. blockIdx.x >= 616 -> covariance body.
// ---------------------------------------------------------------------------
__global__ __launch_bounds__(256) void k_zff(
    const float* __restrict__ Fin, float* __restrict__ M2,
    const float* __restrict__ Wo, const float* __restrict__ bo,
    const float* __restrict__ g2, const float* __restrict__ b2,
    const float* __restrict__ W1, const float* __restrict__ bb1,
    const float* __restrict__ W2, const float* __restrict__ bb2,
    const float* __restrict__ faWq, const float* __restrict__ fabq,
    const float* __restrict__ faWk, const float* __restrict__ fabk,
    const float* __restrict__ faWv, const float* __restrict__ fabv,
    const float* __restrict__ faWout, const float* __restrict__ fabout,
    float* __restrict__ scout,
    const float* __restrict__ M1, float* __restrict__ S,
    float* __restrict__ MU, unsigned* __restrict__ cnt,
    float* __restrict__ covout)
{
    __shared__ float m2l[16 * 68];
    __shared__ float yl[16 * 68];
    __shared__ float zl[16 * 68];
    __shared__ float ul[16 * 260];
    __shared__ unsigned lastf;
    __shared__ float mus[64];
    __shared__ float pa[4], pd[4];
    const int tid = threadIdx.x;

    if (blockIdx.x >= 616) {
        // ---- covariance body, tile aliases ul ----
        float* tile = ul;
        const int cid = blockIdx.x - 616;       // 0..511
        const int bxc = cid & 15, byc = cid >> 4;
        const int ig = tid >> 6, j = tid & 63;
        const int i = bxc * 4 + ig;
        const int l0 = byc * 308;               // 32 * 308 = 9856
        float acc = 0.0f, mua = 0.0f;
        for (int c0 = 0; c0 < 308; c0 += 64) {
            int rows = (308 - c0 < 64) ? (308 - c0) : 64;
            __syncthreads();
            const float4* gsrc = (const float4*)(M1 + (size_t)(l0 + c0) * 64);
            for (int idx = tid; idx < rows * 16; idx += 256)
                *(float4*)&tile[idx * 4] = gsrc[idx];
            __syncthreads();
#pragma unroll 4
            for (int l = 0; l < rows; ++l) {
                float v = tile[l * 64 + j];
                acc += tile[l * 64 + i] * v;
                mua += v;
            }
        }
        atomicAdd(&S[i * 64 + j], acc);
        if (bxc == 0 && ig == 0) atomicAdd(&MU[j], mua);
        __threadfence();
        __syncthreads();
        if (tid == 0) lastf = (atomicAdd(cnt, 1u) == 511u);
        __syncthreads();
        if (lastf) {
            if (tid < 64) mus[tid] = atomicAdd(&MU[tid], 0.0f);
            __syncthreads();
            const float invM = 1.0f / 9856.0f;
            float asum = 0.0f, dsum = 0.0f;
            for (int idx = tid; idx < 4096; idx += 256) {
                int ii = idx >> 6, jj = idx & 63;
                float cc = atomicAdd(&S[idx], 0.0f) * invM
                         - (mus[ii] * invM) * (mus[jj] * invM);
                asum += cc * cc;
                if (ii == jj) dsum += cc * cc;
            }
            for (int o = 32; o; o >>= 1) {
                asum += __shfl_xor(asum, o, 64);
                dsum += __shfl_xor(dsum, o, 64);
            }
            if ((tid & 63) == 0) { pa[tid >> 6] = asum; pd[tid >> 6] = dsum; }
            __syncthreads();
            if (tid == 0)
                covout[128] = 0.5f * ((pa[0] + pa[1] + pa[2] + pa[3])
                                    - (pd[0] + pd[1] + pd[2] + pd[3]));
        }
        return;
    }

    const size_t base = (size_t)blockIdx.x * 16;
    const size_t eb = base * 64;
    const int h = tid & 63, rq = tid >> 6;

    for (int idx = tid; idx < 1024; idx += 256)
        m2l[(idx >> 6) * 68 + (idx & 63)] = M2[eb + idx];
    __syncthreads();

    {
        float acc[4];
#pragma unroll
        for (int rr = 0; rr < 4; ++rr) acc[rr] = bo[h];
        const float4* wo = (const float4*)(Wo + h * 64);
#pragma unroll 4
        for (int c4 = 0; c4 < 16; ++c4) {
            float4 wv = wo[c4];
#pragma unroll
            for (int rr = 0; rr < 4; ++rr) {
                float4 mv = *(const float4*)&m2l[(rq * 4 + rr) * 68 + c4 * 4];
                acc[rr] += mv.x * wv.x + mv.y * wv.y + mv.z * wv.z + mv.w * wv.w;
            }
        }
#pragma unroll
        for (int rr = 0; rr < 4; ++rr) {
            int r = rq * 4 + rr;
            yl[r * 68 + h] = Fin[eb + r * 64 + h] + acc[rr];
        }
    }
    __syncthreads();
    {
        // LN2 parallel: 16 rows x 16 lanes; shfl_xor reduce within 16-lane group
        int row = tid >> 4, l16 = tid & 15;
        float s = 0.0f, s2 = 0.0f;
#pragma unroll
        for (int c = l16; c < 64; c += 16) {
            float vv = yl[row * 68 + c];
            s += vv; s2 += vv * vv;
        }
#pragma unroll
        for (int m = 1; m < 16; m <<= 1) {
            s += __shfl_xor(s, m);
            s2 += __shfl_xor(s2, m);
        }
        float mu = s * (1.0f / 64.0f);
        float var = s2 * (1.0f / 64.0f) - mu * mu;
        float rs = rsqrtf(var + 1e-7f);
#pragma unroll
        for (int c = l16; c < 64; c += 16)
            zl[row * 68 + c] = (yl[row * 68 + c] - mu) * rs * g2[c] + b2[c];
    }
    __syncthreads();

    {
        const int f = tid;
        float acc[16];
#pragma unroll
        for (int r = 0; r < 16; ++r) acc[r] = bb1[f];
        const float4* w1r = (const float4*)(W1 + f * 64);
#pragma unroll
        for (int c = 0; c < 4; ++c) {
            float4 w0 = w1r[c * 4 + 0], w1 = w1r[c * 4 + 1];
            float4 w2 = w1r[c * 4 + 2], w3 = w1r[c * 4 + 3];
#pragma unroll
            for (int r = 0; r < 16; ++r) {
                const float4* zr = (const float4*)&zl[r * 68 + c * 16];
                float4 z0 = zr[0], z1 = zr[1], z2 = zr[2], z3 = zr[3];
                acc[r] += z0.x * w0.x + z0.y * w0.y + z0.z * w0.z + z0.w * w0.w
                        + z1.x * w1.x + z1.y * w1.y + z1.z * w1.z + z1.w * w1.w
                        + z2.x * w2.x + z2.y * w2.y + z2.z * w2.z + z2.w * w2.w
                        + z3.x * w3.x + z3.y * w3.y + z3.z * w3.z + z3.w * w3.w;
            }
        }
#pragma unroll
        for (int r = 0; r < 16; ++r) ul[r * 260 + f] = fmaxf(acc[r], 0.0f);
    }
    __syncthreads();
    {
        float acc[4];
#pragma unroll
        for (int rr = 0; rr < 4; ++rr) acc[rr] = bb2[h];
        const float4* w2r = (const float4*)(W2 + h * 256);
#pragma unroll 4
        for (int c = 0; c < 16; ++c) {
            float4 w0 = w2r[c * 4 + 0], w1 = w2r[c * 4 + 1];
            float4 w2 = w2r[c * 4 + 2], w3 = w2r[c * 4 + 3];
#pragma unroll
            for (int rr = 0; rr < 4; ++rr) {
                const float4* ur = (const float4*)&ul[(rq * 4 + rr) * 260 + c * 16];
                float4 u0 = ur[0], u1 = ur[1], u2 = ur[2], u3 = ur[3];
                acc[rr] += u0.x * w0.x + u0.y * w0.y + u0.z * w0.z + u0.w * w0.w
                         + u1.x * w1.x + u1.y * w1.y + u1.z * w1.z + u1.w * w1.w
                         + u2.x * w2.x + u2.y * w2.y + u2.z * w2.z + u2.w * w2.w
                         + u3.x * w3.x + u3.y * w3.y + u3.z * w3.z + u3.w * w3.w;
            }
        }
#pragma unroll
        for (int rr = 0; rr < 4; ++rr)
            yl[(rq * 4 + rr) * 68 + h] += acc[rr];
    }
    __syncthreads();

    {
        const float4* wq = (const float4*)(faWq + h * 64);
        const float4* wk = (const float4*)(faWk + h * 64);
        const float4* wv = (const float4*)(faWv + h * 64);
        float q[4], k[4], v[4];
#pragma unroll
        for (int rr = 0; rr < 4; ++rr) { q[rr] = fabq[h]; k[rr] = fabk[h]; v[rr] = fabv[h]; }
#pragma unroll 4
        for (int c4 = 0; c4 < 16; ++c4) {
            float4 a = wq[c4], bb = wk[c4], cc = wv[c4];
#pragma unroll
            for (int rr = 0; rr < 4; ++rr) {
                float4 zv = *(const float4*)&yl[(rq * 4 + rr) * 68 + c4 * 4];
                q[rr] += zv.x * a.x + zv.y * a.y + zv.z * a.z + zv.w * a.w;
                k[rr] += zv.x * bb.x + zv.y * bb.y + zv.z * bb.z + zv.w * bb.w;
                v[rr] += zv.x * cc.x + zv.y * cc.y + zv.z * cc.z + zv.w * cc.w;
            }
        }
        float fw = faWout[h];
#pragma unroll
        for (int rr = 0; rr < 4; ++rr) {
            int r = rq * 4 + rr;
            ul[r * 68 + h] = q[rr] * k[rr] * fw;
            M2[eb + r * 64 + h] = v[rr];
        }
    }
    __syncthreads();
    {
        // scout parallel: 16 rows x 16 lanes
        int row = tid >> 4, l16 = tid & 15;
        float a = 0.0f;
#pragma unroll
        for (int c = l16; c < 64; c += 16) a += ul[row * 68 + c];
#pragma unroll
        for (int m = 1; m < 16; m <<= 1) a += __shfl_xor(a, m);
        if (l16 == 0) scout[base + row] = a + fabout[0];
    }
}

// ---------------------------------------------------------------------------
// K7: final softmax + s = alpha.V + output head. grid 128, block 128.
// ---------------------------------------------------------------------------
__global__ __launch_bounds__(128) void k_head(
    const float* __restrict__ Vg, const float* __restrict__ scout,
    const float* __restrict__ o0W, const float* __restrict__ o0b,
    const float* __restrict__ o1W, const float* __restrict__ o1b,
    float* __restrict__ out)
{
    __shared__ float sl[LQ + 3];
    __shared__ float pn[2][64];
    __shared__ float sv[64], h1[64];
    __shared__ float red0;
    const int b = blockIdx.x, tid = threadIdx.x;

    if (tid < LQ) sl[tid] = scout[b * LQ + tid];
    __syncthreads();
    if (tid < 64) {
        float v0 = sl[tid];
        float v1 = (tid < LQ - 64) ? sl[tid + 64] : -1e30f;
        float m = fmaxf(v0, v1);
        for (int o = 32; o; o >>= 1) m = fmaxf(m, __shfl_xor(m, o, 64));
        float e0 = __expf(v0 - m);
        float e1 = (tid < LQ - 64) ? __expf(v1 - m) : 0.0f;
        float s = e0 + e1;
        for (int o = 32; o; o >>= 1) s += __shfl_xor(s, o, 64);
        sl[tid] = e0;
        if (tid < LQ - 64) sl[tid + 64] = e1;
        if (tid == 0) red0 = s;
    }
    __syncthreads();
    {
        int h = tid & 63, half = tid >> 6;
        int l0 = half ? 39 : 0, l1 = half ? LQ : 39;
        float acc = 0.0f;
#pragma unroll 4
        for (int l = l0; l < l1; ++l)
            acc += sl[l] * Vg[((size_t)b * LQ + l) * 64 + h];
        pn[half][h] = acc;
    }
    __syncthreads();
    if (tid < 64) sv[tid] = (pn[0][tid] + pn[1][tid]) * frcp(red0);
    __syncthreads();
    if (tid < 64) {
        float acc = o0b[tid];
        const float4* w = (const float4*)(o0W + tid * 64);
#pragma unroll 4
        for (int c4 = 0; c4 < 16; ++c4) {
            float4 wv = w[c4];
            const float4* sp = (const float4*)&sv[c4 * 4];
            float4 s0 = sp[0];
            acc += s0.x * wv.x + s0.y * wv.y + s0.z * wv.z + s0.w * wv.w;
        }
        h1[tid] = fmaxf(acc, 0.0f);
    }
    __syncthreads();
    if (tid < 64) {
        float p = h1[tid] * o1W[tid];
        for (int o = 32; o; o >>= 1) p += __shfl_xor(p, o, 64);
        if (tid == 0) out[b] = sigmf(p + o1b[0]);
    }
}

// ---------------------------------------------------------------------------
// Fallback path kernels (ws too small).
// ---------------------------------------------------------------------------
__global__ void k_demo(const float* __restrict__ D, const float* __restrict__ dW,
                       const float* __restrict__ db, float* __restrict__ Fin)
{
    int b = blockIdx.x, h = threadIdx.x;
    float acc = db[h];
    for (int j = 0; j < 12; ++j) acc += D[b * 12 + j] * dW[h * 12 + j];
    Fin[((size_t)b * LQ + 76) * HD + h] = tanh_fast(acc);
}

__global__ void k_zero(float* __restrict__ p)
{
    for (int i = threadIdx.x; i < 4161; i += 256) p[i] = 0.0f;
}

__global__ __launch_bounds__(128) void k_gru_mfma(
    const float* __restrict__ X, const float* __restrict__ Wih,
    const float* __restrict__ Whh, const float* __restrict__ bih,
    const float* __restrict__ bhh,
    const float* __restrict__ Wt, const float* __restrict__ bt,
    const float* __restrict__ Wx, const float* __restrict__ bx,
    const float* __restrict__ rate, float* __restrict__ Fin)
{
    __shared__ short As[2][16 * 68];
    __shared__ float xs[16 * 129];
    __shared__ float q1[16 * 65];
    __shared__ float q2[16 * 65];
    __shared__ float qbs[16];
    __shared__ float dotw[2][2][16];

    const int nf = blockIdx.y;
    const int cbase = blockIdx.x * 16;
    const int tid = threadIdx.x;
    const int w = tid >> 6;
    const int lane = tid & 63;
    const int col = lane & 15;
    const int quad = lane >> 4;

    for (int i = tid; i < 16 * T_; i += 128) {
        int b = i >> 7, t = i & 127;
        xs[b * 129 + t] = X[((size_t)(cbase + b) * T_ + t) * NF + nf];
    }
    short8v bfr[3][2][2];
    const float* wbase = Whh + (size_t)nf * 12288;
#pragma unroll
    for (int g3 = 0; g3 < 3; ++g3)
#pragma unroll
        for (int s = 0; s < 2; ++s)
#pragma unroll
            for (int k2 = 0; k2 < 2; ++k2) {
                int g = 64 * g3 + 32 * w + 16 * s + col;
                const float* src = wbase + g * 64 + 32 * k2 + quad * 8;
                float4 f0 = *(const float4*)src;
                float4 f1 = *(const float4*)(src + 4);
                short8v fr;
                fr[0] = tobf(f0.x); fr[1] = tobf(f0.y); fr[2] = tobf(f0.z); fr[3] = tobf(f0.w);
                fr[4] = tobf(f1.x); fr[5] = tobf(f1.y); fr[6] = tobf(f1.z); fr[7] = tobf(f1.w);
                bfr[g3][s][k2] = fr;
            }
    float wr[2], wz[2], wn[2], br[2], bz[2], bnn[2], bhn[2];
#pragma unroll
    for (int s = 0; s < 2; ++s) {
        int c = 32 * w + 16 * s + col;
        int base = nf * 192;
        wr[s] = Wih[base + c]; wz[s] = Wih[base + 64 + c]; wn[s] = Wih[base + 128 + c];
        br[s] = bih[base + c] + bhh[base + c];
        bz[s] = bih[base + 64 + c] + bhh[base + 64 + c];
        bnn[s] = bih[base + 128 + c]; bhn[s] = bhh[base + 128 + c];
    }
    const float sigr = sigmf(rate[nf]);
    float hold[2][4], num[2][4], den[4], qxv[2][4], qbv[4];
#pragma unroll
    for (int r = 0; r < 4; ++r) {
        den[r] = 0.0f; qbv[r] = 0.0f;
        num[0][r] = 0.0f; num[1][r] = 0.0f;
        qxv[0][r] = 0.0f; qxv[1][r] = 0.0f;
    }
    for (int pass = 0; pass < 2; ++pass) {
        for (int i = tid; i < 16 * 68; i += 128) As[0][i] = 0;
#pragma unroll
        for (int s = 0; s < 2; ++s)
#pragma unroll
            for (int r = 0; r < 4; ++r) hold[s][r] = 0.0f;
        __syncthreads();
        for (int t = 0; t < T_; ++t) {
            const int rb = t & 1;
            const int wb = 1 - rb;
            const short* ap = &As[rb][col * 68 + quad * 8];
            short4v a0 = *(const short4v*)ap;
            short4v a1 = *(const short4v*)(ap + 4);
            short4v a2 = *(const short4v*)(ap + 32);
            short4v a3 = *(const short4v*)(ap + 36);
            short8v A0 = {a0[0], a0[1], a0[2], a0[3], a1[0], a1[1], a1[2], a1[3]};
            short8v A1 = {a2[0], a2[1], a2[2], a2[3], a3[0], a3[1], a3[2], a3[3]};
            f32x4 acc[3][2];
#pragma unroll
            for (int g3 = 0; g3 < 3; ++g3)
#pragma unroll
                for (int s = 0; s < 2; ++s) {
                    f32x4 a = {0.0f, 0.0f, 0.0f, 0.0f};
                    a = __builtin_amdgcn_mfma_f32_16x16x32_bf16(A0, bfr[g3][s][0], a, 0, 0, 0);
                    a = __builtin_amdgcn_mfma_f32_16x16x32_bf16(A1, bfr[g3][s][1], a, 0, 0, 0);
                    acc[g3][s] = a;
                }
            float xv[4];
#pragma unroll
            for (int r = 0; r < 4; ++r) xv[r] = xs[(quad * 4 + r) * 129 + t];
            float hnew[2][4];
#pragma unroll
            for (int s = 0; s < 2; ++s)
#pragma unroll
                for (int r = 0; r < 4; ++r) {
                    float rr = sigmf(xv[r] * wr[s] + br[s] + acc[0][s][r]);
                    float zz = sigmf(xv[r] * wz[s] + bz[s] + acc[1][s][r]);
                    float nn = tanh_fast(xv[r] * wn[s] + bnn[s] + rr * (acc[2][s][r] + bhn[s]));
                    hnew[s][r] = (1.0f - zz) * nn + zz * hold[s][r];
                    hold[s][r] = hnew[s][r];
                }
#pragma unroll
            for (int s = 0; s < 2; ++s)
#pragma unroll
                for (int r = 0; r < 4; ++r)
                    As[wb][(quad * 4 + r) * 68 + 32 * w + 16 * s + col] = tobf(hnew[s][r]);
            if (pass == 1) {
                float p[4];
#pragma unroll
                for (int r = 0; r < 4; ++r)
                    p[r] = qxv[0][r] * hnew[0][r] + qxv[1][r] * hnew[1][r];
#pragma unroll
                for (int m = 1; m < 16; m <<= 1) {
                    p[0] += __shfl_xor(p[0], m, 64);
                    p[1] += __shfl_xor(p[1], m, 64);
                    p[2] += __shfl_xor(p[2], m, 64);
                    p[3] += __shfl_xor(p[3], m, 64);
                }
                if (col == 0) {
#pragma unroll
                    for (int r = 0; r < 4; ++r) dotw[rb][w][quad * 4 + r] = p[r];
                }
                __syncthreads();
                float tf = (float)(t + 1);
#pragma unroll
                for (int r = 0; r < 4; ++r) {
                    float dot = p[r] + dotw[rb][1 - w][quad * 4 + r] + qbv[r];
                    float ds = sigmf(dot);
                    float dn = fmaxf(sigr * __logf(2.72f + (1.0f - ds)) * tf, 1e-6f);
                    float e = fmaxf(ds * frcp(dn), 0.0f);
                    float wt = __expf(e);
                    den[r] += wt;
                    num[0][r] += wt * hnew[0][r];
                    num[1][r] += wt * hnew[1][r];
                }
            } else {
                __syncthreads();
            }
        }
        if (pass == 0) {
#pragma unroll
            for (int s = 0; s < 2; ++s)
#pragma unroll
                for (int r = 0; r < 4; ++r)
                    q1[(quad * 4 + r) * 65 + 32 * w + 16 * s + col] = hold[s][r];
            __syncthreads();
            for (int o = tid; o < 16 * 64; o += 128) {
                int b = o >> 6, k = o & 63;
                const float* wrow = Wt + ((size_t)nf * 64 + k) * 64;
                float a = bt[nf * 64 + k];
#pragma unroll 8
                for (int h = 0; h < 64; h += 4) {
                    float4 wv = *(const float4*)&wrow[h];
                    a += q1[b * 65 + h] * wv.x + q1[b * 65 + h + 1] * wv.y
                       + q1[b * 65 + h + 2] * wv.z + q1[b * 65 + h + 3] * wv.w;
                }
                q2[b * 65 + k] = a;
            }
            __syncthreads();
            for (int o = tid; o < 16 * 64; o += 128) {
                int b = o >> 6, h = o & 63;
                float a = 0.0f;
#pragma unroll 8
                for (int k = 0; k < 64; ++k)
                    a += q2[b * 65 + k] * Wx[((size_t)nf * 64 + k) * 64 + h];
                q1[b * 65 + h] = a;
            }
            for (int b = tid; b < 16; b += 128) {
                float a = 0.0f;
                for (int k = 0; k < 64; ++k) a += q2[b * 65 + k] * bx[nf * 64 + k];
                qbs[b] = a;
            }
            __syncthreads();
#pragma unroll
            for (int r = 0; r < 4; ++r) {
                qbv[r] = qbs[quad * 4 + r];
#pragma unroll
                for (int s = 0; s < 2; ++s)
                    qxv[s][r] = q1[(quad * 4 + r) * 65 + 32 * w + 16 * s + col];
                den[r] = 0.0f; num[0][r] = 0.0f; num[1][r] = 0.0f;
            }
            __syncthreads();
        }
    }
#pragma unroll
    for (int s = 0; s < 2; ++s)
#pragma unroll
        for (int r = 0; r < 4; ++r) {
            int b = cbase + quad * 4 + r;
            int c = 32 * w + 16 * s + col;
            Fin[((size_t)b * LQ + nf) * HD + c] = num[s][r] * frcp(den[r]);
        }
}

extern "C" void kernel_launch(void* const* d_in, const int* in_sizes, int n_in,
                              void* d_out, int out_size, void* d_ws, size_t ws_size,
                              hipStream_t stream)
{
    (void)in_sizes; (void)n_in; (void)out_size;
    const float* X     = (const float*)d_in[0];
    const float* D     = (const float*)d_in[1];
    const float* gWih  = (const float*)d_in[2];
    const float* gWhh  = (const float*)d_in[3];
    const float* gbih  = (const float*)d_in[4];
    const float* gbhh  = (const float*)d_in[5];
    const float* aWt   = (const float*)d_in[6];
    const float* abt   = (const float*)d_in[7];
    const float* aWx   = (const float*)d_in[8];
    const float* abx   = (const float*)d_in[9];
    const float* arate = (const float*)d_in[10];
    const float* dW    = (const float*)d_in[11];
    const float* db    = (const float*)d_in[12];
    const float* mWq   = (const float*)d_in[13]; const float* mbq = (const float*)d_in[14];
    const float* mWk   = (const float*)d_in[15]; const float* mbk = (const float*)d_in[16];
    const float* mWv   = (const float*)d_in[17]; const float* mbv = (const float*)d_in[18];
    const float* mWo   = (const float*)d_in[19]; const float* mbo = (const float*)d_in[20];
    const float* l1g   = (const float*)d_in[21]; const float* l1b = (const float*)d_in[22];
    const float* fW1   = (const float*)d_in[23]; const float* fb1 = (const float*)d_in[24];
    const float* fW2   = (const float*)d_in[25]; const float* fb2 = (const float*)d_in[26];
    const float* l2g   = (const float*)d_in[27]; const float* l2b = (const float*)d_in[28];
    const float* faWq  = (const float*)d_in[29]; const float* fabq = (const float*)d_in[30];
    const float* faWk  = (const float*)d_in[31]; const float* fabk = (const float*)d_in[32];
    const float* faWv  = (const float*)d_in[33]; const float* fabv = (const float*)d_in[34];
    const float* faWo  = (const float*)d_in[35]; const float* fabo = (const float*)d_in[36];
    const float* o0W   = (const float*)d_in[37]; const float* o0b  = (const float*)d_in[38];
    const float* o1W   = (const float*)d_in[39]; const float* o1b  = (const float*)d_in[40];

    float* ws  = (float*)d_ws;
    float* Fin = ws;                               // 630,784
    float* M1  = Fin + 630784;                     // 630,784
    float* M2  = M1  + 630784;                     // 630,784 (later reused as V)
    float* S   = M2  + 630784;                     // 4096
    float* MU  = S   + 4096;                       // 64
    unsigned* cnt = (unsigned*)(MU + 64);          // 1 (+63 pad)
    float* qxg = MU + 128;                         // 622,592
    float* scout = qxg + 622592;                   // 9,856 (also used as qbg)
    short* Hsg = (short*)(scout + 9856);           // 79,691,776 shorts (bf16)
    const size_t need = (size_t)(630784 * 3 + 4096 + 128 + 622592 + 9856) * 4
                        + (size_t)79691776 * 2;
    float* outp = (float*)d_out;
    float* qbg = scout;                            // alias: qbg consumed before scout written

    if (ws_size >= need) {
        k_gru0<<<608, 256, 0, stream>>>(X, gWih, gWhh, gbih, gbhh,
                                        aWt, abt, aWx, abx, Hsg, qxg, qbg);
        k_att<<<dim3(NF + 1, B_), 128, 0, stream>>>(Hsg, qxg, qbg, arate,
                                                    D, dW, db, S, Fin);
    } else {
        k_gru_mfma<<<dim3(8, NF), 128, 0, stream>>>(X, gWih, gWhh, gbih, gbhh,
                                                    aWt, abt, aWx, abx, arate, Fin);
        k_demo<<<B_, 64, 0, stream>>>(D, dW, db, Fin);
        k_zero<<<1, 256, 0, stream>>>(S);
    }
    k_mha2<<<dim3(B_, 4, 2), 256, 0, stream>>>(Fin, mWq, mbq, mWk, mbk, mWv, mbv,
                                               l1g, l1b, M1, M2);
    k_zff<<<1128, 256, 0, stream>>>(Fin, M2, mWo, mbo, l2g, l2b,
                                    fW1, fb1, fW2, fb2,
                                    faWq, fabq, faWk, fabk, faWv, fabv,
                                    faWo, fabo, scout,
                                    M1, S, MU, cnt, outp);
    k_head<<<B_, 128, 0, stream>>>(M2, scout, o0W, o0b, o1W, o1b, outp);
}

// Round 10
// 491.656 us; speedup vs baseline: 1.2229x; 1.0174x over previous
//
#include <hip/hip_runtime.h>
#include <math.h>

#define B_ 128
#define T_ 128
#define NF 76
#define HD 64
#define LQ 77

typedef __attribute__((ext_vector_type(8))) short short8v;
typedef __attribute__((ext_vector_type(4))) short short4v;
typedef __attribute__((ext_vector_type(4))) float f32x4;

__device__ __forceinline__ float frcp(float x) { return __builtin_amdgcn_rcpf(x); }
__device__ __forceinline__ float sigmf(float x) { return frcp(1.0f + __expf(-x)); }
// sigm2: sigmoid with argument already scaled by log2(e) (exp2 domain)
__device__ __forceinline__ float sigm2(float x) { return frcp(1.0f + __builtin_amdgcn_exp2f(-x)); }
__device__ __forceinline__ float tanh_fast(float x) { return 2.0f * frcp(1.0f + __expf(-2.0f * x)) - 1.0f; }
__device__ __forceinline__ short tobf(float x) {
    unsigned u = __float_as_uint(x);
    u += 0x7FFF + ((u >> 16) & 1);   // RNE to bf16
    return (short)(u >> 16);
}
__device__ __forceinline__ float bflo(unsigned u) { return __uint_as_float(u << 16); }
__device__ __forceinline__ float bfhi(unsigned u) { return __uint_as_float(u & 0xffff0000u); }

// ---------------------------------------------------------------------------
// K1a: GRU recurrence via MFMA. R15 structure (measured 139us / total 492us,
// session best): 16 rows, 4 waves, 608 blocks, 8-deep ring, burst stores,
// bias-in-C, exp2-domain gates, setprio around MFMA.
// Refuted alternatives: dual-feature blocks (R12), wave-autonomous (R13),
// 8-row pad (R14), fused attention (R16), spin-gated merges (R17),
// micro-opts on tail kernels (R18 — all within noise).
// ---------------------------------------------------------------------------
__global__ __launch_bounds__(256) void k_gru0(
    const float* __restrict__ X, const float* __restrict__ Wih,
    const float* __restrict__ Whh, const float* __restrict__ bih,
    const float* __restrict__ bhh,
    const float* __restrict__ Wt, const float* __restrict__ bt,
    const float* __restrict__ Wx, const float* __restrict__ bx,
    short* __restrict__ Hsg, float* __restrict__ qxg, float* __restrict__ qbg)
{
    __shared__ short As[8][16 * 68];    // h ring: As[t&7] = h_t
    __shared__ float xs[16 * 129];
    __shared__ float q1[16 * 65];
    __shared__ float q2[16 * 65];

    const int nf = blockIdx.y;
    const int cbase = blockIdx.x * 16;
    const int tid = threadIdx.x;
    const int w = tid >> 6;
    const int lane = tid & 63;
    const int col = lane & 15;
    const int quad = lane >> 4;

    const float S1 = 1.44269504f;       // log2(e)
    const float S2 = 2.88539008f;       // 2*log2(e)

    for (int i = tid; i < 16 * T_; i += 256) {
        int b = i >> 7, t = i & 127;
        xs[b * 129 + t] = X[((size_t)(cbase + b) * T_ + t) * NF + nf];
    }

    short8v bfr[3][2];
    const float* wbase = Whh + (size_t)nf * 12288;
#pragma unroll
    for (int g3 = 0; g3 < 3; ++g3) {
        const float sc = (g3 == 2) ? S2 : S1;
#pragma unroll
        for (int k2 = 0; k2 < 2; ++k2) {
            int g = 64 * g3 + 16 * w + col;
            const float* src = wbase + g * 64 + 32 * k2 + quad * 8;
            float4 f0 = *(const float4*)src;
            float4 f1 = *(const float4*)(src + 4);
            short8v fr;
            fr[0] = tobf(f0.x * sc); fr[1] = tobf(f0.y * sc);
            fr[2] = tobf(f0.z * sc); fr[3] = tobf(f0.w * sc);
            fr[4] = tobf(f1.x * sc); fr[5] = tobf(f1.y * sc);
            fr[6] = tobf(f1.z * sc); fr[7] = tobf(f1.w * sc);
            bfr[g3][k2] = fr;
        }
    }

    const int c = 16 * w + col;
    const int base = nf * 192;
    const float wr = Wih[base + c] * S1;
    const float wz = Wih[base + 64 + c] * S1;
    const float wn = Wih[base + 128 + c] * S2;
    const float bnn = bih[base + 128 + c] * S2;
    f32x4 biasC[3];
    {
        float brr = (bih[base + c] + bhh[base + c]) * S1;
        float bzz = (bih[base + 64 + c] + bhh[base + 64 + c]) * S1;
        float bhn = bhh[base + 128 + c] * S2;
        biasC[0] = (f32x4){brr, brr, brr, brr};
        biasC[1] = (f32x4){bzz, bzz, bzz, bzz};
        biasC[2] = (f32x4){bhn, bhn, bhn, bhn};
    }

    for (int i = tid; i < 16 * 68; i += 256) As[7][i] = 0;   // h_{-1} = 0
    float hold[4];
#pragma unroll
    for (int r = 0; r < 4; ++r) hold[r] = 0.0f;
    __syncthreads();

    for (int t = 0; t < T_; ++t) {
        const int rb = (t + 7) & 7;     // h_{t-1}
        const int wb = t & 7;           // h_t
        const short* ap = &As[rb][col * 68 + quad * 8];
        short4v a0 = *(const short4v*)ap;
        short4v a1 = *(const short4v*)(ap + 4);
        short4v a2 = *(const short4v*)(ap + 32);
        short4v a3 = *(const short4v*)(ap + 36);
        short8v A0 = {a0[0], a0[1], a0[2], a0[3], a1[0], a1[1], a1[2], a1[3]};
        short8v A1 = {a2[0], a2[1], a2[2], a2[3], a3[0], a3[1], a3[2], a3[3]};

        __builtin_amdgcn_s_setprio(1);
        f32x4 acc[3];
#pragma unroll
        for (int g3 = 0; g3 < 3; ++g3) {
            f32x4 a = __builtin_amdgcn_mfma_f32_16x16x32_bf16(
                A0, bfr[g3][0], biasC[g3], 0, 0, 0);
            acc[g3] = __builtin_amdgcn_mfma_f32_16x16x32_bf16(
                A1, bfr[g3][1], a, 0, 0, 0);
        }
        __builtin_amdgcn_s_setprio(0);

#pragma unroll
        for (int r = 0; r < 4; ++r) {
            float xv = xs[(quad * 4 + r) * 129 + t];
            float rr = sigm2(fmaf(xv, wr, acc[0][r]));
            float zz = sigm2(fmaf(xv, wz, acc[1][r]));
            float uu = sigm2(fmaf(rr, acc[2][r], fmaf(xv, wn, bnn)));
            float nn = fmaf(2.0f, uu, -1.0f);
            hold[r] = fmaf(zz, hold[r] - nn, nn);
        }

#pragma unroll
        for (int r = 0; r < 4; ++r)
            As[wb][(quad * 4 + r) * 68 + c] = tobf(hold[r]);
        __syncthreads();

        if ((t & 7) == 7) {
            // Burst-store h_{t-7}..h_t: LDS reads, barrier, then global stores
            // (drain lands a full step later).
            const int oct = tid & 7, bb = (tid >> 3) & 15, k0 = tid >> 7;
            short4v r0[4], r1[4];
#pragma unroll
            for (int s = 0; s < 4; ++s) {
                const short* p = &As[k0 + 2 * s][bb * 68 + oct * 8];
                r0[s] = *(const short4v*)p;
                r1[s] = *(const short4v*)(p + 4);
            }
            __syncthreads();
            const size_t gbase =
                (((size_t)nf * 128 + cbase + bb) * 128 + (t - 7)) * 64 + oct * 8;
#pragma unroll
            for (int s = 0; s < 4; ++s) {
                short8v v = {r0[s][0], r0[s][1], r0[s][2], r0[s][3],
                             r1[s][0], r1[s][1], r1[s][2], r1[s][3]};
                *(short8v*)(Hsg + gbase + (size_t)(k0 + 2 * s) * 64) = v;
            }
        }
    }

#pragma unroll
    for (int r = 0; r < 4; ++r)
        q1[(quad * 4 + r) * 65 + c] = hold[r];
    __syncthreads();
    for (int o = tid; o < 16 * 64; o += 256) {
        int b = o >> 6, k = o & 63;
        const float* wrow = Wt + ((size_t)nf * 64 + k) * 64;
        float a = bt[nf * 64 + k];
#pragma unroll 8
        for (int h = 0; h < 64; h += 4) {
            float4 wv = *(const float4*)&wrow[h];
            a += q1[b * 65 + h] * wv.x + q1[b * 65 + h + 1] * wv.y
               + q1[b * 65 + h + 2] * wv.z + q1[b * 65 + h + 3] * wv.w;
        }
        q2[b * 65 + k] = a;
    }
    __syncthreads();
    for (int o = tid; o < 16 * 64; o += 256) {
        int b = o >> 6, h = o & 63;
        float a = 0.0f;
#pragma unroll 8
        for (int k = 0; k < 64; ++k)
            a += q2[b * 65 + k] * Wx[((size_t)nf * 64 + k) * 64 + h];
        qxg[((size_t)nf * 128 + cbase + b) * 64 + h] = a;
    }
    for (int b = tid; b < 16; b += 256) {
        float a = 0.0f;
        for (int k = 0; k < 64; ++k) a += q2[b * 65 + k] * bx[nf * 64 + k];
        qbg[nf * 128 + cbase + b] = a;
    }
}

// ---------------------------------------------------------------------------
// K1b: time attention + demo row + S/MU/counter zeroing. grid (77,128).
// ---------------------------------------------------------------------------
__global__ __launch_bounds__(128) void k_att(
    const short* __restrict__ Hsg, const float* __restrict__ qxg,
    const float* __restrict__ qbg, const float* __restrict__ rate,
    const float* __restrict__ D, const float* __restrict__ dW,
    const float* __restrict__ db, float* __restrict__ Sz,
    float* __restrict__ Fin)
{
    const int nf = blockIdx.x, b = blockIdx.y;
    const int tid = threadIdx.x;

    if (nf == NF) {
        if (tid < 64) {
            float acc = db[tid];
            for (int j = 0; j < 12; ++j) acc += D[b * 12 + j] * dW[tid * 12 + j];
            Fin[((size_t)b * LQ + 76) * HD + tid] = tanh_fast(acc);
        }
        int s0 = b * 33;
        for (int k = tid; k < 33; k += 128) {
            int idx = s0 + k;
            if (idx < 4161) Sz[idx] = 0.0f;
        }
        return;
    }

    __shared__ float wsum[128 * 69];
    __shared__ float wl[128];
    __shared__ float qxl[64];
    __shared__ float pn[2][68];
    __shared__ float pd[2];
    if (tid < 64) qxl[tid] = qxg[((size_t)nf * 128 + b) * 64 + tid];
    const float qb = qbg[nf * 128 + b];
    const float sigr = sigmf(rate[nf]);

    uint4 rv[8];
    const uint4* src = (const uint4*)(Hsg + (((size_t)nf * 128 + b) * 128 + tid) * 64);
#pragma unroll
    for (int k = 0; k < 8; ++k) rv[k] = src[k];
    __syncthreads();

    float a = qb;
#pragma unroll
    for (int k = 0; k < 8; ++k) {
        a += bflo(rv[k].x) * qxl[k * 8 + 0] + bfhi(rv[k].x) * qxl[k * 8 + 1]
           + bflo(rv[k].y) * qxl[k * 8 + 2] + bfhi(rv[k].y) * qxl[k * 8 + 3]
           + bflo(rv[k].z) * qxl[k * 8 + 4] + bfhi(rv[k].z) * qxl[k * 8 + 5]
           + bflo(rv[k].w) * qxl[k * 8 + 6] + bfhi(rv[k].w) * qxl[k * 8 + 7];
    }
    float ds = sigmf(a);
    float dn = fmaxf(sigr * __logf(2.72f + (1.0f - ds)) * (float)(tid + 1), 1e-6f);
    float e = fmaxf(ds * frcp(dn), 0.0f);
    float w = __expf(e);
    wl[tid] = w;
#pragma unroll
    for (int k = 0; k < 8; ++k) {
        float* d = &wsum[tid * 69 + k * 8];
        d[0] = w * bflo(rv[k].x); d[1] = w * bfhi(rv[k].x);
        d[2] = w * bflo(rv[k].y); d[3] = w * bfhi(rv[k].y);
        d[4] = w * bflo(rv[k].z); d[5] = w * bfhi(rv[k].z);
        d[6] = w * bflo(rv[k].w); d[7] = w * bfhi(rv[k].w);
    }
    __syncthreads();
    {
        int ch = tid & 63, half = tid >> 6;
        float acc = 0.0f, den = 0.0f;
        int t0 = half * 64;
        for (int t = t0; t < t0 + 64; ++t) {
            acc += wsum[t * 69 + ch];
            den += wl[t];
        }
        pn[half][ch] = acc;
        if (ch == 0) pd[half] = den;
    }
    __syncthreads();
    if (tid < 64) {
        float num = pn[0][tid] + pn[1][tid];
        float den = pd[0] + pd[1];
        Fin[((size_t)b * LQ + nf) * HD + tid] = num * frcp(den);
    }
}

// ---------------------------------------------------------------------------
// K4: MHA per (b, head, variant). grid (128,4,2), block 256.
// ---------------------------------------------------------------------------
__global__ __launch_bounds__(256) void k_mha2(
    const float* __restrict__ Fin,
    const float* __restrict__ Wq, const float* __restrict__ bq,
    const float* __restrict__ Wk, const float* __restrict__ bk,
    const float* __restrict__ Wv, const float* __restrict__ bv,
    const float* __restrict__ g1, const float* __restrict__ b1,
    float* __restrict__ M1, float* __restrict__ M2)
{
    __shared__ float xl[LQ * 68];       // later reused as os[231][17]
    __shared__ float qh[LQ * 20], kh[LQ * 20], vh[LQ * 20];
    float (*os)[17] = (float (*)[17])xl;
    const int b = blockIdx.x, hd = blockIdx.y, v = blockIdx.z;
    const int tid = threadIdx.x;
    const float* xsrc = Fin + (size_t)b * LQ * HD;

    for (int idx = tid; idx < LQ * HD; idx += 256)
        xl[(idx >> 6) * 68 + (idx & 63)] = xsrc[idx];
    __syncthreads();
    if (v == 1) {
        if (tid < LQ) {
            float mu = 0.0f;
            for (int h = 0; h < 64; ++h) mu += xl[tid * 68 + h];
            mu *= (1.0f / 64.0f);
            float var = 0.0f;
            for (int h = 0; h < 64; ++h) { float d = xl[tid * 68 + h] - mu; var += d * d; }
            var *= (1.0f / 64.0f);
            float rs = rsqrtf(var + 1e-7f);
            for (int h = 0; h < 64; ++h)
                xl[tid * 68 + h] = (xl[tid * 68 + h] - mu) * rs * g1[h] + b1[h];
        }
        __syncthreads();
    }

    for (int idx = tid; idx < LQ * 16; idx += 256) {
        int l = idx >> 4, d = idx & 15, ch = hd * 16 + d;
        float aq = bq[ch], ak = bk[ch], av = bv[ch];
        const float4* wq = (const float4*)(Wq + ch * 64);
        const float4* wk = (const float4*)(Wk + ch * 64);
        const float4* wv = (const float4*)(Wv + ch * 64);
        const float4* xr = (const float4*)&xl[l * 68];
#pragma unroll 4
        for (int c4 = 0; c4 < 16; ++c4) {
            float4 xv = xr[c4];
            float4 a = wq[c4], bb = wk[c4], cc = wv[c4];
            aq += xv.x * a.x + xv.y * a.y + xv.z * a.z + xv.w * a.w;
            ak += xv.x * bb.x + xv.y * bb.y + xv.z * bb.z + xv.w * bb.w;
            av += xv.x * cc.x + xv.y * cc.y + xv.z * cc.z + xv.w * cc.w;
        }
        qh[l * 20 + d] = aq; kh[l * 20 + d] = ak; vh[l * 20 + d] = av;
    }
    __syncthreads();   // QKV done; xl dead -> reuse as os

    if (tid < 231) {
        int l = tid % 77, third = tid / 77;
        float4 qf0 = *(const float4*)&qh[l * 20 + 0];
        float4 qf1 = *(const float4*)&qh[l * 20 + 4];
        float4 qf2 = *(const float4*)&qh[l * 20 + 8];
        float4 qf3 = *(const float4*)&qh[l * 20 + 12];
        int j0 = third * 26;
        int j1 = (third == 2) ? LQ : j0 + 26;
        float o[16];
#pragma unroll
        for (int d = 0; d < 16; ++d) o[d] = 0.0f;
        float ss = 0.0f;
        for (int j = j0; j < j1; ++j) {
            const float4* kp = (const float4*)&kh[j * 20];
            float4 k0 = kp[0], k1 = kp[1], k2 = kp[2], k3 = kp[3];
            float sc = qf0.x * k0.x + qf0.y * k0.y + qf0.z * k0.z + qf0.w * k0.w
                     + qf1.x * k1.x + qf1.y * k1.y + qf1.z * k1.z + qf1.w * k1.w
                     + qf2.x * k2.x + qf2.y * k2.y + qf2.z * k2.z + qf2.w * k2.w
                     + qf3.x * k3.x + qf3.y * k3.y + qf3.z * k3.z + qf3.w * k3.w;
            float p = __expf(sc * 0.25f);   // scores tiny: no max-shift
            ss += p;
            const float4* vp = (const float4*)&vh[j * 20];
            float4 v0 = vp[0], v1 = vp[1], v2 = vp[2], v3 = vp[3];
            o[0] += p * v0.x; o[1] += p * v0.y; o[2] += p * v0.z; o[3] += p * v0.w;
            o[4] += p * v1.x; o[5] += p * v1.y; o[6] += p * v1.z; o[7] += p * v1.w;
            o[8] += p * v2.x; o[9] += p * v2.y; o[10] += p * v2.z; o[11] += p * v2.w;
            o[12] += p * v3.x; o[13] += p * v3.y; o[14] += p * v3.z; o[15] += p * v3.w;
        }
#pragma unroll
        for (int d = 0; d < 16; ++d) os[tid][d] = o[d];
        os[tid][16] = ss;
    }
    __syncthreads();
    if (tid < LQ) {
        float inv = frcp(os[tid][16] + os[77 + tid][16] + os[154 + tid][16]);
        float* Mout = (v == 1) ? M2 : M1;
#pragma unroll
        for (int d = 0; d < 16; ++d)
            Mout[((size_t)b * LQ + tid) * HD + hd * 16 + d]
                = (os[tid][d] + os[77 + tid][d] + os[154 + tid][d]) * inv;
    }
}

// ---------------------------------------------------------------------------
// K5: fused Y + LN2 + FFN + final-QKV + score, PLUS covariance blocks.
// grid 616 + 512 = 1128, block 256. blockIdx.x >= 616 -> covariance body.
// ---------------------------------------------------------------------------
__global__ __launch_bounds__(256) void k_zff(
    const float* __restrict__ Fin, float* __restrict__ M2,
    const float* __restrict__ Wo, const float* __restrict__ bo,
    const float* __restrict__ g2, const float* __restrict__ b2,
    const float* __restrict__ W1, const float* __restrict__ bb1,
    const float* __restrict__ W2, const float* __restrict__ bb2,
    const float* __restrict__ faWq, const float* __restrict__ fabq,
    const float* __restrict__ faWk, const float* __restrict__ fabk,
    const float* __restrict__ faWv, const float* __restrict__ fabv,
    const float* __restrict__ faWout, const float* __restrict__ fabout,
    float* __restrict__ scout,
    const float* __restrict__ M1, float* __restrict__ S,
    float* __restrict__ MU, unsigned* __restrict__ cnt,
    float* __restrict__ covout)
{
    __shared__ float m2l[16 * 68];
    __shared__ float yl[16 * 68];
    __shared__ float zl[16 * 68];
    __shared__ float ul[16 * 260];
    __shared__ unsigned lastf;
    __shared__ float mus[64];
    __shared__ float pa[4], pd[4];
    const int tid = threadIdx.x;

    if (blockIdx.x >= 616) {
        // ---- covariance body, tile aliases ul ----
        float* tile = ul;
        const int cid = blockIdx.x - 616;       // 0..511
        const int bxc = cid & 15, byc = cid >> 4;
        const int ig = tid >> 6, j = tid & 63;
        const int i = bxc * 4 + ig;
        const int l0 = byc * 308;               // 32 * 308 = 9856
        float acc = 0.0f, mua = 0.0f;
        for (int c0 = 0; c0 < 308; c0 += 64) {
            int rows = (308 - c0 < 64) ? (308 - c0) : 64;
            __syncthreads();
            const float4* gsrc = (const float4*)(M1 + (size_t)(l0 + c0) * 64);
            for (int idx = tid; idx < rows * 16; idx += 256)
                *(float4*)&tile[idx * 4] = gsrc[idx];
            __syncthreads();
#pragma unroll 4
            for (int l = 0; l < rows; ++l) {
                float v = tile[l * 64 + j];
                acc += tile[l * 64 + i] * v;
                mua += v;
            }
        }
        atomicAdd(&S[i * 64 + j], acc);
        if (bxc == 0 && ig == 0) atomicAdd(&MU[j], mua);
        __threadfence();
        __syncthreads();
        if (tid == 0) lastf = (atomicAdd(cnt, 1u) == 511u);
        __syncthreads();
        if (lastf) {
            if (tid < 64) mus[tid] = atomicAdd(&MU[tid], 0.0f);
            __syncthreads();
            const float invM = 1.0f / 9856.0f;
            float asum = 0.0f, dsum = 0.0f;
            for (int idx = tid; idx < 4096; idx += 256) {
                int ii = idx >> 6, jj = idx & 63;
                float cc = atomicAdd(&S[idx], 0.0f) * invM
                         - (mus[ii] * invM) * (mus[jj] * invM);
                asum += cc * cc;
                if (ii == jj) dsum += cc * cc;
            }
            for (int o = 32; o; o >>= 1) {
                asum += __shfl_xor(asum, o, 64);
                dsum += __shfl_xor(dsum, o, 64);
            }
            if ((tid & 63) == 0) { pa[tid >> 6] = asum; pd[tid >> 6] = dsum; }
            __syncthreads();
            if (tid == 0)
                covout[128] = 0.5f * ((pa[0] + pa[1] + pa[2] + pa[3])
                                    - (pd[0] + pd[1] + pd[2] + pd[3]));
        }
        return;
    }

    const size_t base = (size_t)blockIdx.x * 16;
    const size_t eb = base * 64;
    const int h = tid & 63, rq = tid >> 6;

    for (int idx = tid; idx < 1024; idx += 256)
        m2l[(idx >> 6) * 68 + (idx & 63)] = M2[eb + idx];
    __syncthreads();

    {
        float acc[4];
#pragma unroll
        for (int rr = 0; rr < 4; ++rr) acc[rr] = bo[h];
        const float4* wo = (const float4*)(Wo + h * 64);
#pragma unroll 4
        for (int c4 = 0; c4 < 16; ++c4) {
            float4 wv = wo[c4];
#pragma unroll
            for (int rr = 0; rr < 4; ++rr) {
                float4 mv = *(const float4*)&m2l[(rq * 4 + rr) * 68 + c4 * 4];
                acc[rr] += mv.x * wv.x + mv.y * wv.y + mv.z * wv.z + mv.w * wv.w;
            }
        }
#pragma unroll
        for (int rr = 0; rr < 4; ++rr) {
            int r = rq * 4 + rr;
            yl[r * 68 + h] = Fin[eb + r * 64 + h] + acc[rr];
        }
    }
    __syncthreads();
    if (tid < 16) {
        float mu = 0.0f;
        for (int c = 0; c < 64; ++c) mu += yl[tid * 68 + c];
        mu *= (1.0f / 64.0f);
        float var = 0.0f;
        for (int c = 0; c < 64; ++c) { float d = yl[tid * 68 + c] - mu; var += d * d; }
        var *= (1.0f / 64.0f);
        float rs = rsqrtf(var + 1e-7f);
        for (int c = 0; c < 64; ++c)
            zl[tid * 68 + c] = (yl[tid * 68 + c] - mu) * rs * g2[c] + b2[c];
    }
    __syncthreads();

    {
        const int f = tid;
        float acc[16];
#pragma unroll
        for (int r = 0; r < 16; ++r) acc[r] = bb1[f];
        const float4* w1r = (const float4*)(W1 + f * 64);
#pragma unroll
        for (int c = 0; c < 4; ++c) {
            float4 w0 = w1r[c * 4 + 0], w1 = w1r[c * 4 + 1];
            float4 w2 = w1r[c * 4 + 2], w3 = w1r[c * 4 + 3];
#pragma unroll
            for (int r = 0; r < 16; ++r) {
                const float4* zr = (const float4*)&zl[r * 68 + c * 16];
                float4 z0 = zr[0], z1 = zr[1], z2 = zr[2], z3 = zr[3];
                acc[r] += z0.x * w0.x + z0.y * w0.y + z0.z * w0.z + z0.w * w0.w
                        + z1.x * w1.x + z1.y * w1.y + z1.z * w1.z + z1.w * w1.w
                        + z2.x * w2.x + z2.y * w2.y + z2.z * w2.z + z2.w * w2.w
                        + z3.x * w3.x + z3.y * w3.y + z3.z * w3.z + z3.w * w3.w;
            }
        }
#pragma unroll
        for (int r = 0; r < 16; ++r) ul[r * 260 + f] = fmaxf(acc[r], 0.0f);
    }
    __syncthreads();
    {
        float acc[4];
#pragma unroll
        for (int rr = 0; rr < 4; ++rr) acc[rr] = bb2[h];
        const float4* w2r = (const float4*)(W2 + h * 256);
#pragma unroll 4
        for (int c = 0; c < 16; ++c) {
            float4 w0 = w2r[c * 4 + 0], w1 = w2r[c * 4 + 1];
            float4 w2 = w2r[c * 4 + 2], w3 = w2r[c * 4 + 3];
#pragma unroll
            for (int rr = 0; rr < 4; ++rr) {
                const float4* ur = (const float4*)&ul[(rq * 4 + rr) * 260 + c * 16];
                float4 u0 = ur[0], u1 = ur[1], u2 = ur[2], u3 = ur[3];
                acc[rr] += u0.x * w0.x + u0.y * w0.y + u0.z * w0.z + u0.w * w0.w
                         + u1.x * w1.x + u1.y * w1.y + u1.z * w1.z + u1.w * w1.w
                         + u2.x * w2.x + u2.y * w2.y + u2.z * w2.z + u2.w * w2.w
                         + u3.x * w3.x + u3.y * w3.y + u3.z * w3.z + u3.w * w3.w;
            }
        }
#pragma unroll
        for (int rr = 0; rr < 4; ++rr)
            yl[(rq * 4 + rr) * 68 + h] += acc[rr];
    }
    __syncthreads();

    {
        const float4* wq = (const float4*)(faWq + h * 64);
        const float4* wk = (const float4*)(faWk + h * 64);
        const float4* wv = (const float4*)(faWv + h * 64);
        float q[4], k[4], v[4];
#pragma unroll
        for (int rr = 0; rr < 4; ++rr) { q[rr] = fabq[h]; k[rr] = fabk[h]; v[rr] = fabv[h]; }
#pragma unroll 4
        for (int c4 = 0; c4 < 16; ++c4) {
            float4 a = wq[c4], bb = wk[c4], cc = wv[c4];
#pragma unroll
            for (int rr = 0; rr < 4; ++rr) {
                float4 zv = *(const float4*)&yl[(rq * 4 + rr) * 68 + c4 * 4];
                q[rr] += zv.x * a.x + zv.y * a.y + zv.z * a.z + zv.w * a.w;
                k[rr] += zv.x * bb.x + zv.y * bb.y + zv.z * bb.z + zv.w * bb.w;
                v[rr] += zv.x * cc.x + zv.y * cc.y + zv.z * cc.z + zv.w * cc.w;
            }
        }
        float fw = faWout[h];
#pragma unroll
        for (int rr = 0; rr < 4; ++rr) {
            int r = rq * 4 + rr;
            ul[r * 68 + h] = q[rr] * k[rr] * fw;
            M2[eb + r * 64 + h] = v[rr];
        }
    }
    __syncthreads();
    if (tid < 16) {
        float a = fabout[0];
        for (int c = 0; c < 64; ++c) a += ul[tid * 68 + c];
        scout[base + tid] = a;
    }
}

// ---------------------------------------------------------------------------
// K7: final softmax + s = alpha.V + output head. grid 128, block 128.
// ---------------------------------------------------------------------------
__global__ __launch_bounds__(128) void k_head(
    const float* __restrict__ Vg, const float* __restrict__ scout,
    const float* __restrict__ o0W, const float* __restrict__ o0b,
    const float* __restrict__ o1W, const float* __restrict__ o1b,
    float* __restrict__ out)
{
    __shared__ float sl[LQ + 3];
    __shared__ float pn[2][64];
    __shared__ float sv[64], h1[64];
    __shared__ float red0;
    const int b = blockIdx.x, tid = threadIdx.x;

    if (tid < LQ) sl[tid] = scout[b * LQ + tid];
    __syncthreads();
    if (tid < 64) {
        float v0 = sl[tid];
        float v1 = (tid < LQ - 64) ? sl[tid + 64] : -1e30f;
        float m = fmaxf(v0, v1);
        for (int o = 32; o; o >>= 1) m = fmaxf(m, __shfl_xor(m, o, 64));
        float e0 = __expf(v0 - m);
        float e1 = (tid < LQ - 64) ? __expf(v1 - m) : 0.0f;
        float s = e0 + e1;
        for (int o = 32; o; o >>= 1) s += __shfl_xor(s, o, 64);
        sl[tid] = e0;
        if (tid < LQ - 64) sl[tid + 64] = e1;
        if (tid == 0) red0 = s;
    }
    __syncthreads();
    {
        int h = tid & 63, half = tid >> 6;
        int l0 = half ? 39 : 0, l1 = half ? LQ : 39;
        float acc = 0.0f;
#pragma unroll 4
        for (int l = l0; l < l1; ++l)
            acc += sl[l] * Vg[((size_t)b * LQ + l) * 64 + h];
        pn[half][h] = acc;
    }
    __syncthreads();
    if (tid < 64) sv[tid] = (pn[0][tid] + pn[1][tid]) * frcp(red0);
    __syncthreads();
    if (tid < 64) {
        float acc = o0b[tid];
        const float4* w = (const float4*)(o0W + tid * 64);
#pragma unroll 4
        for (int c4 = 0; c4 < 16; ++c4) {
            float4 wv = w[c4];
            const float4* sp = (const float4*)&sv[c4 * 4];
            float4 s0 = sp[0];
            acc += s0.x * wv.x + s0.y * wv.y + s0.z * wv.z + s0.w * wv.w;
        }
        h1[tid] = fmaxf(acc, 0.0f);
    }
    __syncthreads();
    if (tid < 64) {
        float p = h1[tid] * o1W[tid];
        for (int o = 32; o; o >>= 1) p += __shfl_xor(p, o, 64);
        if (tid == 0) out[b] = sigmf(p + o1b[0]);
    }
}

// ---------------------------------------------------------------------------
// Fallback path kernels (ws too small).
// ---------------------------------------------------------------------------
__global__ void k_demo(const float* __restrict__ D, const float* __restrict__ dW,
                       const float* __restrict__ db, float* __restrict__ Fin)
{
    int b = blockIdx.x, h = threadIdx.x;
    float acc = db[h];
    for (int j = 0; j < 12; ++j) acc += D[b * 12 + j] * dW[h * 12 + j];
    Fin[((size_t)b * LQ + 76) * HD + h] = tanh_fast(acc);
}

__global__ void k_zero(float* __restrict__ p)
{
    for (int i = threadIdx.x; i < 4161; i += 256) p[i] = 0.0f;
}

__global__ __launch_bounds__(128) void k_gru_mfma(
    const float* __restrict__ X, const float* __restrict__ Wih,
    const float* __restrict__ Whh, const float* __restrict__ bih,
    const float* __restrict__ bhh,
    const float* __restrict__ Wt, const float* __restrict__ bt,
    const float* __restrict__ Wx, const float* __restrict__ bx,
    const float* __restrict__ rate, float* __restrict__ Fin)
{
    __shared__ short As[2][16 * 68];
    __shared__ float xs[16 * 129];
    __shared__ float q1[16 * 65];
    __shared__ float q2[16 * 65];
    __shared__ float qbs[16];
    __shared__ float dotw[2][2][16];

    const int nf = blockIdx.y;
    const int cbase = blockIdx.x * 16;
    const int tid = threadIdx.x;
    const int w = tid >> 6;
    const int lane = tid & 63;
    const int col = lane & 15;
    const int quad = lane >> 4;

    for (int i = tid; i < 16 * T_; i += 128) {
        int b = i >> 7, t = i & 127;
        xs[b * 129 + t] = X[((size_t)(cbase + b) * T_ + t) * NF + nf];
    }
    short8v bfr[3][2][2];
    const float* wbase = Whh + (size_t)nf * 12288;
#pragma unroll
    for (int g3 = 0; g3 < 3; ++g3)
#pragma unroll
        for (int s = 0; s < 2; ++s)
#pragma unroll
            for (int k2 = 0; k2 < 2; ++k2) {
                int g = 64 * g3 + 32 * w + 16 * s + col;
                const float* src = wbase + g * 64 + 32 * k2 + quad * 8;
                float4 f0 = *(const float4*)src;
                float4 f1 = *(const float4*)(src + 4);
                short8v fr;
                fr[0] = tobf(f0.x); fr[1] = tobf(f0.y); fr[2] = tobf(f0.z); fr[3] = tobf(f0.w);
                fr[4] = tobf(f1.x); fr[5] = tobf(f1.y); fr[6] = tobf(f1.z); fr[7] = tobf(f1.w);
                bfr[g3][s][k2] = fr;
            }
    float wr[2], wz[2], wn[2], br[2], bz[2], bnn[2], bhn[2];
#pragma unroll
    for (int s = 0; s < 2; ++s) {
        int c = 32 * w + 16 * s + col;
        int base = nf * 192;
        wr[s] = Wih[base + c]; wz[s] = Wih[base + 64 + c]; wn[s] = Wih[base + 128 + c];
        br[s] = bih[base + c] + bhh[base + c];
        bz[s] = bih[base + 64 + c] + bhh[base + 64 + c];
        bnn[s] = bih[base + 128 + c]; bhn[s] = bhh[base + 128 + c];
    }
    const float sigr = sigmf(rate[nf]);
    float hold[2][4], num[2][4], den[4], qxv[2][4], qbv[4];
#pragma unroll
    for (int r = 0; r < 4; ++r) {
        den[r] = 0.0f; qbv[r] = 0.0f;
        num[0][r] = 0.0f; num[1][r] = 0.0f;
        qxv[0][r] = 0.0f; qxv[1][r] = 0.0f;
    }
    for (int pass = 0; pass < 2; ++pass) {
        for (int i = tid; i < 16 * 68; i += 128) As[0][i] = 0;
#pragma unroll
        for (int s = 0; s < 2; ++s)
#pragma unroll
            for (int r = 0; r < 4; ++r) hold[s][r] = 0.0f;
        __syncthreads();
        for (int t = 0; t < T_; ++t) {
            const int rb = t & 1;
            const int wb = 1 - rb;
            const short* ap = &As[rb][col * 68 + quad * 8];
            short4v a0 = *(const short4v*)ap;
            short4v a1 = *(const short4v*)(ap + 4);
            short4v a2 = *(const short4v*)(ap + 32);
            short4v a3 = *(const short4v*)(ap + 36);
            short8v A0 = {a0[0], a0[1], a0[2], a0[3], a1[0], a1[1], a1[2], a1[3]};
            short8v A1 = {a2[0], a2[1], a2[2], a2[3], a3[0], a3[1], a3[2], a3[3]};
            f32x4 acc[3][2];
#pragma unroll
            for (int g3 = 0; g3 < 3; ++g3)
#pragma unroll
                for (int s = 0; s < 2; ++s) {
                    f32x4 a = {0.0f, 0.0f, 0.0f, 0.0f};
                    a = __builtin_amdgcn_mfma_f32_16x16x32_bf16(A0, bfr[g3][s][0], a, 0, 0, 0);
                    a = __builtin_amdgcn_mfma_f32_16x16x32_bf16(A1, bfr[g3][s][1], a, 0, 0, 0);
                    acc[g3][s] = a;
                }
            float xv[4];
#pragma unroll
            for (int r = 0; r < 4; ++r) xv[r] = xs[(quad * 4 + r) * 129 + t];
            float hnew[2][4];
#pragma unroll
            for (int s = 0; s < 2; ++s)
#pragma unroll
                for (int r = 0; r < 4; ++r) {
                    float rr = sigmf(xv[r] * wr[s] + br[s] + acc[0][s][r]);
                    float zz = sigmf(xv[r] * wz[s] + bz[s] + acc[1][s][r]);
                    float nn = tanh_fast(xv[r] * wn[s] + bnn[s] + rr * (acc[2][s][r] + bhn[s]));
                    hnew[s][r] = (1.0f - zz) * nn + zz * hold[s][r];
                    hold[s][r] = hnew[s][r];
                }
#pragma unroll
            for (int s = 0; s < 2; ++s)
#pragma unroll
                for (int r = 0; r < 4; ++r)
                    As[wb][(quad * 4 + r) * 68 + 32 * w + 16 * s + col] = tobf(hnew[s][r]);
            if (pass == 1) {
                float p[4];
#pragma unroll
                for (int r = 0; r < 4; ++r)
                    p[r] = qxv[0][r] * hnew[0][r] + qxv[1][r] * hnew[1][r];
#pragma unroll
                for (int m = 1; m < 16; m <<= 1) {
                    p[0] += __shfl_xor(p[0], m, 64);
                    p[1] += __shfl_xor(p[1], m, 64);
                    p[2] += __shfl_xor(p[2], m, 64);
                    p[3] += __shfl_xor(p[3], m, 64);
                }
                if (col == 0) {
#pragma unroll
                    for (int r = 0; r < 4; ++r) dotw[rb][w][quad * 4 + r] = p[r];
                }
                __syncthreads();
                float tf = (float)(t + 1);
#pragma unroll
                for (int r = 0; r < 4; ++r) {
                    float dot = p[r] + dotw[rb][1 - w][quad * 4 + r] + qbv[r];
                    float ds = sigmf(dot);
                    float dn = fmaxf(sigr * __logf(2.72f + (1.0f - ds)) * tf, 1e-6f);
                    float e = fmaxf(ds * frcp(dn), 0.0f);
                    float wt = __expf(e);
                    den[r] += wt;
                    num[0][r] += wt * hnew[0][r];
                    num[1][r] += wt * hnew[1][r];
                }
            } else {
                __syncthreads();
            }
        }
        if (pass == 0) {
#pragma unroll
            for (int s = 0; s < 2; ++s)
#pragma unroll
                for (int r = 0; r < 4; ++r)
                    q1[(quad * 4 + r) * 65 + 32 * w + 16 * s + col] = hold[s][r];
            __syncthreads();
            for (int o = tid; o < 16 * 64; o += 128) {
                int b = o >> 6, k = o & 63;
                const float* wrow = Wt + ((size_t)nf * 64 + k) * 64;
                float a = bt[nf * 64 + k];
#pragma unroll 8
                for (int h = 0; h < 64; h += 4) {
                    float4 wv = *(const float4*)&wrow[h];
                    a += q1[b * 65 + h] * wv.x + q1[b * 65 + h + 1] * wv.y
                       + q1[b * 65 + h + 2] * wv.z + q1[b * 65 + h + 3] * wv.w;
                }
                q2[b * 65 + k] = a;
            }
            __syncthreads();
            for (int o = tid; o < 16 * 64; o += 128) {
                int b = o >> 6, h = o & 63;
                float a = 0.0f;
#pragma unroll 8
                for (int k = 0; k < 64; ++k)
                    a += q2[b * 65 + k] * Wx[((size_t)nf * 64 + k) * 64 + h];
                q1[b * 65 + h] = a;
            }
            for (int b = tid; b < 16; b += 128) {
                float a = 0.0f;
                for (int k = 0; k < 64; ++k) a += q2[b * 65 + k] * bx[nf * 64 + k];
                qbs[b] = a;
            }
            __syncthreads();
#pragma unroll
            for (int r = 0; r < 4; ++r) {
                qbv[r] = qbs[quad * 4 + r];
#pragma unroll
                for (int s = 0; s < 2; ++s)
                    qxv[s][r] = q1[(quad * 4 + r) * 65 + 32 * w + 16 * s + col];
                den[r] = 0.0f; num[0][r] = 0.0f; num[1][r] = 0.0f;
            }
            __syncthreads();
        }
    }
#pragma unroll
    for (int s = 0; s < 2; ++s)
#pragma unroll
        for (int r = 0; r < 4; ++r) {
            int b = cbase + quad * 4 + r;
            int c = 32 * w + 16 * s + col;
            Fin[((size_t)b * LQ + nf) * HD + c] = num[s][r] * frcp(den[r]);
        }
}

extern "C" void kernel_launch(void* const* d_in, const int* in_sizes, int n_in,
                              void* d_out, int out_size, void* d_ws, size_t ws_size,
                              hipStream_t stream)
{
    (void)in_sizes; (void)n_in; (void)out_size;
    const float* X     = (const float*)d_in[0];
    const float* D     = (const float*)d_in[1];
    const float* gWih  = (const float*)d_in[2];
    const float* gWhh  = (const float*)d_in[3];
    const float* gbih  = (const float*)d_in[4];
    const float* gbhh  = (const float*)d_in[5];
    const float* aWt   = (const float*)d_in[6];
    const float* abt   = (const float*)d_in[7];
    const float* aWx   = (const float*)d_in[8];
    const float* abx   = (const float*)d_in[9];
    const float* arate = (const float*)d_in[10];
    const float* dW    = (const float*)d_in[11];
    const float* db    = (const float*)d_in[12];
    const float* mWq   = (const float*)d_in[13]; const float* mbq = (const float*)d_in[14];
    const float* mWk   = (const float*)d_in[15]; const float* mbk = (const float*)d_in[16];
    const float* mWv   = (const float*)d_in[17]; const float* mbv = (const float*)d_in[18];
    const float* mWo   = (const float*)d_in[19]; const float* mbo = (const float*)d_in[20];
    const float* l1g   = (const float*)d_in[21]; const float* l1b = (const float*)d_in[22];
    const float* fW1   = (const float*)d_in[23]; const float* fb1 = (const float*)d_in[24];
    const float* fW2   = (const float*)d_in[25]; const float* fb2 = (const float*)d_in[26];
    const float* l2g   = (const float*)d_in[27]; const float* l2b = (const float*)d_in[28];
    const float* faWq  = (const float*)d_in[29]; const float* fabq = (const float*)d_in[30];
    const float* faWk  = (const float*)d_in[31]; const float* fabk = (const float*)d_in[32];
    const float* faWv  = (const float*)d_in[33]; const float* fabv = (const float*)d_in[34];
    const float* faWo  = (const float*)d_in[35]; const float* fabo = (const float*)d_in[36];
    const float* o0W   = (const float*)d_in[37]; const float* o0b  = (const float*)d_in[38];
    const float* o1W   = (const float*)d_in[39]; const float* o1b  = (const float*)d_in[40];

    float* ws  = (float*)d_ws;
    float* Fin = ws;                               // 630,784
    float* M1  = Fin + 630784;                     // 630,784
    float* M2  = M1  + 630784;                     // 630,784 (later reused as V)
    float* S   = M2  + 630784;                     // 4096
    float* MU  = S   + 4096;                       // 64
    unsigned* cnt = (unsigned*)(MU + 64);          // 1 (+63 pad)
    float* qxg = MU + 128;                         // 622,592
    float* scout = qxg + 622592;                   // 9,856 (also used as qbg)
    short* Hsg = (short*)(scout + 9856);           // 79,691,776 shorts (bf16)
    const size_t need = (size_t)(630784 * 3 + 4096 + 128 + 622592 + 9856) * 4
                        + (size_t)79691776 * 2;
    float* outp = (float*)d_out;
    float* qbg = scout;                            // alias: qbg consumed before scout written

    if (ws_size >= need) {
        k_gru0<<<dim3(8, NF), 256, 0, stream>>>(X, gWih, gWhh, gbih, gbhh,
                                                aWt, abt, aWx, abx, Hsg, qxg, qbg);
        k_att<<<dim3(NF + 1, B_), 128, 0, stream>>>(Hsg, qxg, qbg, arate,
                                                    D, dW, db, S, Fin);
    } else {
        k_gru_mfma<<<dim3(8, NF), 128, 0, stream>>>(X, gWih, gWhh, gbih, gbhh,
                                                    aWt, abt, aWx, abx, arate, Fin);
        k_demo<<<B_, 64, 0, stream>>>(D, dW, db, Fin);
        k_zero<<<1, 256, 0, stream>>>(S);
    }
    k_mha2<<<dim3(B_, 4, 2), 256, 0, stream>>>(Fin, mWq, mbq, mWk, mbk, mWv, mbv,
                                               l1g, l1b, M1, M2);
    k_zff<<<1128, 256, 0, stream>>>(Fin, M2, mWo, mbo, l2g, l2b,
                                    fW1, fb1, fW2, fb2,
                                    faWq, fabq, faWk, fabk, faWv, fabv,
                                    faWo, fabo, scout,
                                    M1, S, MU, cnt, outp);
    k_head<<<B_, 128, 0, stream>>>(M2, scout, o0W, o0b, o1W, o1b, outp);
}